// Round 1
// baseline (606.895 us; speedup 1.0000x reference)
//
#include <hip/hip_runtime.h>
#include <math.h>

// Problem constants (match reference setup_inputs)
#define SB 196   // spatial s = h*w = 14*14
#define NB 8     // batch
#define NC 2048  // channels
#define ND 1024  // INTER_DIM
#define NN 80    // NUM_CLASSES
#define NW 300   // WORD_DIM

// ---------------------------------------------------------------------------
// K0a: v[d] = sum_e Wa[e] * W3[e][d]   (Wa @ W3), accumulated via atomics.
// grid (4, 16), block 256: d = bx*256+t, e-chunk = by*64..+64
// ---------------------------------------------------------------------------
__global__ __launch_bounds__(256) void k0_v(const float* __restrict__ W3,
                                            const float* __restrict__ Wa,
                                            float* __restrict__ v) {
    int d  = blockIdx.x * 256 + threadIdx.x;
    int e0 = blockIdx.y * 64;
    float p = 0.f;
    #pragma unroll 8
    for (int e = e0; e < e0 + 64; ++e) {
        p += Wa[e] * W3[(size_t)e * ND + d];   // coalesced over d
    }
    atomicAdd(&v[d], p);
}

// ---------------------------------------------------------------------------
// K0b: fwd[n][d] = sum_w word[n][w] * W2[d][w]
// grid (80, 4), block 256: n = bx, d = by*256+t
// ---------------------------------------------------------------------------
__global__ __launch_bounds__(256) void k0_fwd(const float* __restrict__ word,
                                              const float* __restrict__ W2,
                                              float* __restrict__ fwd) {
    __shared__ __align__(16) float lword[NW];
    int n = blockIdx.x;
    int d = blockIdx.y * 256 + threadIdx.x;
    for (int i = threadIdx.x; i < NW; i += 256) lword[i] = word[(size_t)n * NW + i];
    __syncthreads();
    const float4* wr = (const float4*)(W2 + (size_t)d * NW);   // 300*4B = 16B-aligned rows
    const float4* l4 = (const float4*)lword;
    float acc = 0.f;
    #pragma unroll 5
    for (int i = 0; i < NW / 4; ++i) {
        float4 a = wr[i], b = l4[i];
        acc += a.x * b.x + a.y * b.y + a.z * b.z + a.w * b.w;
    }
    fwd[(size_t)n * ND + d] = acc;
}

// ---------------------------------------------------------------------------
// K1: F[b][d][s] = sum_c W1[d][c] * X[b][c][s]
// fp32 tiled GEMM: per-block tile (b, 64 d, 64 s), 4x4 micro-tile/thread.
// grid (16 d-tiles, 4 s-tiles, 8 b), block 256
// ---------------------------------------------------------------------------
#define TD 64
#define TS 64
#define KC 32
__global__ __launch_bounds__(256) void k1_fwh(const float* __restrict__ X,
                                              const float* __restrict__ W1,
                                              float* __restrict__ F) {
    __shared__ float ldsW[KC][TD + 4];  // [k][d], +4 pad: 16B-aligned rows, kills write conflicts
    __shared__ float ldsX[KC][TS];      // [k][s]
    const int t  = threadIdx.x;
    const int d0 = blockIdx.x * TD;
    const int s0 = blockIdx.y * TS;
    const int b  = blockIdx.z;
    const int dg = t & 15;   // 16 d-groups of 4
    const int sg = t >> 4;   // 16 s-groups of 4
    const float* Xb = X + (size_t)b * NC * SB;

    float acc[4][4];
    #pragma unroll
    for (int i = 0; i < 4; ++i)
        #pragma unroll
        for (int j = 0; j < 4; ++j) acc[i][j] = 0.f;

    for (int k0 = 0; k0 < NC; k0 += KC) {
        // stage W1 tile (rows = d, cols = k) transposed into ldsW[k][d]
        #pragma unroll
        for (int i = t; i < TD * KC; i += 256) {
            int dd = i >> 5;        // /KC
            int kk = i & (KC - 1);
            ldsW[kk][dd] = W1[(size_t)(d0 + dd) * NC + k0 + kk];
        }
        // stage X tile [k][s] (zero-pad s >= 196)
        #pragma unroll
        for (int i = t; i < KC * TS; i += 256) {
            int kk = i >> 6;
            int ss = i & 63;
            int s  = s0 + ss;
            ldsX[kk][ss] = (s < SB) ? Xb[(size_t)(k0 + kk) * SB + s] : 0.f;
        }
        __syncthreads();
        #pragma unroll 8
        for (int kk = 0; kk < KC; ++kk) {
            float a[4], bb[4];
            #pragma unroll
            for (int i = 0; i < 4; ++i) a[i]  = ldsW[kk][dg * 4 + i];
            #pragma unroll
            for (int j = 0; j < 4; ++j) bb[j] = ldsX[kk][sg * 4 + j];
            #pragma unroll
            for (int i = 0; i < 4; ++i)
                #pragma unroll
                for (int j = 0; j < 4; ++j) acc[i][j] += a[i] * bb[j];
        }
        __syncthreads();
    }
    // write F[b][d][s]
    float* Fb = F + (size_t)b * ND * SB;
    #pragma unroll
    for (int i = 0; i < 4; ++i) {
        int d = d0 + dg * 4 + i;
        float* row = Fb + (size_t)d * SB;
        #pragma unroll
        for (int j = 0; j < 4; ++j) {
            int s = s0 + sg * 4 + j;
            if (s < SB) row[s] = acc[i][j];
        }
    }
}

// ---------------------------------------------------------------------------
// K2: logits l[s] = sum_d v[d] * tanh(F[b][d][s] * fwd[n][d]); softmax over s;
// write coef[b][n][s]. One block per (n, b); thread = s (196 active of 256).
// ---------------------------------------------------------------------------
__global__ __launch_bounds__(256) void k2_coef(const float* __restrict__ F,
                                               const float* __restrict__ fwd,
                                               const float* __restrict__ v,
                                               float* __restrict__ coef) {
    __shared__ float lv[ND];
    __shared__ float lw[ND];
    __shared__ float red[256];
    const int n = blockIdx.x;
    const int b = blockIdx.y;
    const int t = threadIdx.x;
    for (int i = t; i < ND; i += 256) {
        lv[i] = v[i];
        lw[i] = fwd[(size_t)n * ND + i];
    }
    __syncthreads();

    float acc = 0.f;
    const float* Fb = F + (size_t)b * ND * SB;
    if (t < SB) {
        #pragma unroll 8
        for (int d = 0; d < ND; ++d) {
            float x = Fb[(size_t)d * SB + t] * lw[d];
            // tanh(x) = 1 - 2/(exp(2x)+1), fast exp + fast rcp
            float e = __expf(2.f * x);
            float r = __builtin_amdgcn_rcpf(e + 1.f);
            acc += lv[d] * (1.f - 2.f * r);
        }
    }
    // block softmax over s (196 valid lanes)
    red[t] = (t < SB) ? acc : -1e30f;
    __syncthreads();
    #pragma unroll
    for (int off = 128; off > 0; off >>= 1) {
        if (t < off) red[t] = fmaxf(red[t], red[t + off]);
        __syncthreads();
    }
    float m = red[0];
    __syncthreads();
    float p = (t < SB) ? __expf(acc - m) : 0.f;
    red[t] = p;
    __syncthreads();
    #pragma unroll
    for (int off = 128; off > 0; off >>= 1) {
        if (t < off) red[t] += red[t + off];
        __syncthreads();
    }
    float inv = 1.f / red[0];
    if (t < SB) coef[((size_t)b * NN + n) * SB + t] = p * inv;
}

// ---------------------------------------------------------------------------
// K3: out[b][n][c] = sum_s X[b][c][s] * coef[b][n][s]
// grid (20 n-tiles of 4, 32 c-tiles of 64, 8 b), block 256 = 64c x 4n
// K=196 contiguous in both operands -> per-lane float4 dots, coef broadcast.
// ---------------------------------------------------------------------------
__global__ __launch_bounds__(256) void k3_out(const float* __restrict__ X,
                                              const float* __restrict__ coef,
                                              float* __restrict__ out) {
    const int t = threadIdx.x;
    const int c = blockIdx.y * 64 + (t & 63);
    const int n = blockIdx.x * 4 + (t >> 6);
    const int b = blockIdx.z;
    const float4* xr = (const float4*)(X + ((size_t)b * NC + c) * SB);    // 784B rows: 16B aligned
    const float4* cr = (const float4*)(coef + ((size_t)b * NN + n) * SB);
    float acc = 0.f;
    #pragma unroll 7
    for (int i = 0; i < SB / 4; ++i) {
        float4 a = xr[i], w = cr[i];
        acc += a.x * w.x + a.y * w.y + a.z * w.z + a.w * w.w;
    }
    out[((size_t)b * NN + n) * NC + c] = acc;
}

// ---------------------------------------------------------------------------
extern "C" void kernel_launch(void* const* d_in, const int* in_sizes, int n_in,
                              void* d_out, int out_size, void* d_ws, size_t ws_size,
                              hipStream_t stream) {
    const float* X    = (const float*)d_in[0];  // [8][2048][196]
    const float* word = (const float*)d_in[1];  // [80][300]
    const float* W1   = (const float*)d_in[2];  // [1024][2048]
    const float* W2   = (const float*)d_in[3];  // [1024][300]
    const float* W3   = (const float*)d_in[4];  // [1024][1024]
    // d_in[5] = b3, d_in[7] = ba: cancel in softmax (uniform over s) -> unused
    const float* Wa   = (const float*)d_in[6];  // [1][1024]
    float* out = (float*)d_out;

    float* ws   = (float*)d_ws;
    float* v    = ws;                            // 1024
    float* fwd  = v + ND;                        // 80*1024
    float* F    = fwd + (size_t)NN * ND;         // 8*1024*196
    float* coef = F + (size_t)NB * ND * SB;      // 8*80*196
    // total ~1.81M floats ~= 7.3 MB of d_ws

    hipMemsetAsync(v, 0, ND * sizeof(float), stream);
    k0_v  <<<dim3(4, 16),        256, 0, stream>>>(W3, Wa, v);
    k0_fwd<<<dim3(NN, 4),        256, 0, stream>>>(word, W2, fwd);
    k1_fwh<<<dim3(16, 4, NB),    256, 0, stream>>>(X, W1, F);
    k2_coef<<<dim3(NN, NB),      256, 0, stream>>>(F, fwd, v, coef);
    k3_out<<<dim3(20, 32, NB),   256, 0, stream>>>(X, coef, out);
}

// Round 2
// 299.200 us; speedup vs baseline: 2.0284x; 2.0284x over previous
//
#include <hip/hip_runtime.h>
#include <math.h>

// Problem constants (match reference setup_inputs)
#define SB 196   // spatial s = h*w = 14*14
#define NB 8     // batch
#define NC 2048  // channels
#define ND 1024  // INTER_DIM
#define NN 80    // NUM_CLASSES
#define NW 300   // WORD_DIM

typedef __bf16 v8bf __attribute__((ext_vector_type(8)));
typedef __bf16 v4bf __attribute__((ext_vector_type(4)));
typedef float  f32x4 __attribute__((ext_vector_type(4)));

// ---------------------------------------------------------------------------
// K0a: v[d] = sum_e Wa[e] * W3[e][d]   (Wa @ W3), accumulated via atomics.
// ---------------------------------------------------------------------------
__global__ __launch_bounds__(256) void k0_v(const float* __restrict__ W3,
                                            const float* __restrict__ Wa,
                                            float* __restrict__ v) {
    int d  = blockIdx.x * 256 + threadIdx.x;
    int e0 = blockIdx.y * 64;
    float p = 0.f;
    #pragma unroll 8
    for (int e = e0; e < e0 + 64; ++e) {
        p += Wa[e] * W3[(size_t)e * ND + d];   // coalesced over d
    }
    atomicAdd(&v[d], p);
}

// ---------------------------------------------------------------------------
// K0b: fwd[n][d] = sum_w word[n][w] * W2[d][w]
// ---------------------------------------------------------------------------
__global__ __launch_bounds__(256) void k0_fwd(const float* __restrict__ word,
                                              const float* __restrict__ W2,
                                              float* __restrict__ fwd) {
    __shared__ __align__(16) float lword[NW];
    int n = blockIdx.x;
    int d = blockIdx.y * 256 + threadIdx.x;
    for (int i = threadIdx.x; i < NW; i += 256) lword[i] = word[(size_t)n * NW + i];
    __syncthreads();
    const float4* wr = (const float4*)(W2 + (size_t)d * NW);
    const float4* l4 = (const float4*)lword;
    float acc = 0.f;
    #pragma unroll 5
    for (int i = 0; i < NW / 4; ++i) {
        float4 a = wr[i], b = l4[i];
        acc += a.x * b.x + a.y * b.y + a.z * b.z + a.w * b.w;
    }
    fwd[(size_t)n * ND + d] = acc;
}

// ---------------------------------------------------------------------------
// Cast W1 [1024][2048] fp32 -> bf16, same layout. 2M elems / 4 per thread.
// ---------------------------------------------------------------------------
__global__ __launch_bounds__(256) void kcast_w1(const float* __restrict__ W1,
                                                __bf16* __restrict__ O) {
    size_t i = ((size_t)blockIdx.x * 256 + threadIdx.x) * 4;
    float4 f = *(const float4*)(W1 + i);
    v4bf o;
    o[0] = (__bf16)f.x; o[1] = (__bf16)f.y; o[2] = (__bf16)f.z; o[3] = (__bf16)f.w;
    *(v4bf*)(O + i) = o;
}

// ---------------------------------------------------------------------------
// Cast+transpose X [b][c][s] fp32 -> Xt [b][s][c] bf16 (LDS-tiled 64x64).
// grid (32 c-tiles, 4 s-tiles, 8 b)
// ---------------------------------------------------------------------------
__global__ __launch_bounds__(256) void kcast_x(const float* __restrict__ X,
                                               __bf16* __restrict__ Xt) {
    __shared__ float tile[64][65];   // [c][s], +1 pad
    const int b  = blockIdx.z;
    const int c0 = blockIdx.x * 64;
    const int s0 = blockIdx.y * 64;
    const int t  = threadIdx.x;
    const float* Xb = X + (size_t)b * NC * SB;
    {   // read: coalesced over s
        int ss = t & 63, cbase = t >> 6;
        #pragma unroll
        for (int r = 0; r < 16; ++r) {
            int cc = cbase + 4 * r;
            float val = (s0 + ss < SB) ? Xb[(size_t)(c0 + cc) * SB + s0 + ss] : 0.f;
            tile[cc][ss] = val;
        }
    }
    __syncthreads();
    {   // write: coalesced over c
        int cc = t & 63, sbase = t >> 6;
        #pragma unroll
        for (int r = 0; r < 16; ++r) {
            int ss = sbase + 4 * r;
            if (s0 + ss < SB)
                Xt[((size_t)b * SB + s0 + ss) * NC + c0 + cc] = (__bf16)tile[cc][ss];
        }
    }
}

// ---------------------------------------------------------------------------
// K1 (MFMA): F[b][d][s] = sum_c W1[d][c] * X[b][c][s], bf16 inputs, fp32 out.
// Block tile 64d x 64s, 4 waves each own a 32x32 quadrant (2x2 16x16 frags).
// K-step 32. A = W1b [d][c] rows; B = Xt [s][c] rows (both c-contiguous).
// LDS rows padded to 80 B (40 shorts): 16B-aligned, 2-way bank alias only.
// grid (16 d-tiles, 4 s-tiles, 8 b), block 256.
// ---------------------------------------------------------------------------
#define PITCH 40
__global__ __launch_bounds__(256) void k1_mfma(const __bf16* __restrict__ Xt,
                                               const __bf16* __restrict__ W1b,
                                               float* __restrict__ F) {
    __shared__ __align__(16) __bf16 lA[64 * PITCH];
    __shared__ __align__(16) __bf16 lB[64 * PITCH];
    const int t    = threadIdx.x;
    const int d0   = blockIdx.x * 64;
    const int s0   = blockIdx.y * 64;
    const int b    = blockIdx.z;
    const int lane = t & 63;
    const int wave = t >> 6;
    const int doff = (wave & 1) * 32;
    const int soff = (wave >> 1) * 32;
    const int quad = lane >> 4;
    const int l16  = lane & 15;

    f32x4 acc[2][2] = {};

    // staging assignment: thread -> (row rr, 8 consecutive c at cc)
    const int rr = t >> 2;
    const int cc = (t & 3) * 8;
    const bool sv = (s0 + rr) < SB;
    const __bf16* Ag = W1b + (size_t)(d0 + rr) * NC + cc;
    const __bf16* Bg = Xt + ((size_t)b * SB + (sv ? (s0 + rr) : 0)) * NC + cc;
    __bf16* lAw = lA + rr * PITCH + cc;
    __bf16* lBw = lB + rr * PITCH + cc;

    const __bf16* rA0 = lA + (doff + l16) * PITCH + quad * 8;
    const __bf16* rA1 = rA0 + 16 * PITCH;
    const __bf16* rB0 = lB + (soff + l16) * PITCH + quad * 8;
    const __bf16* rB1 = rB0 + 16 * PITCH;

    for (int k0 = 0; k0 < NC; k0 += 32) {
        uint4 a = *(const uint4*)(Ag + k0);
        uint4 bv = sv ? *(const uint4*)(Bg + k0) : make_uint4(0u, 0u, 0u, 0u);
        __syncthreads();               // prev-iter LDS reads done before overwrite
        *(uint4*)lAw = a;
        *(uint4*)lBw = bv;
        __syncthreads();
        v8bf a0 = *(const v8bf*)rA0;
        v8bf a1 = *(const v8bf*)rA1;
        v8bf b0 = *(const v8bf*)rB0;
        v8bf b1 = *(const v8bf*)rB1;
        acc[0][0] = __builtin_amdgcn_mfma_f32_16x16x32_bf16(a0, b0, acc[0][0], 0, 0, 0);
        acc[0][1] = __builtin_amdgcn_mfma_f32_16x16x32_bf16(a0, b1, acc[0][1], 0, 0, 0);
        acc[1][0] = __builtin_amdgcn_mfma_f32_16x16x32_bf16(a1, b0, acc[1][0], 0, 0, 0);
        acc[1][1] = __builtin_amdgcn_mfma_f32_16x16x32_bf16(a1, b1, acc[1][1], 0, 0, 0);
    }
    // epilogue: D[row=quad*4+r (d), col=l16 (s)]
    float* Fb = F + (size_t)b * ND * SB;
    #pragma unroll
    for (int i = 0; i < 2; ++i) {
        #pragma unroll
        for (int j = 0; j < 2; ++j) {
            int s = s0 + soff + j * 16 + l16;
            if (s < SB) {
                #pragma unroll
                for (int r = 0; r < 4; ++r) {
                    int d = d0 + doff + i * 16 + quad * 4 + r;
                    Fb[(size_t)d * SB + s] = acc[i][j][r];
                }
            }
        }
    }
}

// ---------------------------------------------------------------------------
// K2: logits l[s] = sum_d v[d] * tanh(F[b][d][s] * fwd[n][d]); softmax over s;
// write coef[b][n][s]. One block per (n, b); thread = s (196 active of 256).
// ---------------------------------------------------------------------------
__global__ __launch_bounds__(256) void k2_coef(const float* __restrict__ F,
                                               const float* __restrict__ fwd,
                                               const float* __restrict__ v,
                                               float* __restrict__ coef) {
    __shared__ float lv[ND];
    __shared__ float lw[ND];
    __shared__ float red[256];
    const int n = blockIdx.x;
    const int b = blockIdx.y;
    const int t = threadIdx.x;
    for (int i = t; i < ND; i += 256) {
        lv[i] = v[i];
        lw[i] = fwd[(size_t)n * ND + i];
    }
    __syncthreads();

    float acc = 0.f;
    const float* Fb = F + (size_t)b * ND * SB;
    if (t < SB) {
        #pragma unroll 8
        for (int d = 0; d < ND; ++d) {
            float x = Fb[(size_t)d * SB + t] * lw[d];
            float e = __expf(2.f * x);
            float r = __builtin_amdgcn_rcpf(e + 1.f);
            acc += lv[d] * (1.f - 2.f * r);
        }
    }
    red[t] = (t < SB) ? acc : -1e30f;
    __syncthreads();
    #pragma unroll
    for (int off = 128; off > 0; off >>= 1) {
        if (t < off) red[t] = fmaxf(red[t], red[t + off]);
        __syncthreads();
    }
    float m = red[0];
    __syncthreads();
    float p = (t < SB) ? __expf(acc - m) : 0.f;
    red[t] = p;
    __syncthreads();
    #pragma unroll
    for (int off = 128; off > 0; off >>= 1) {
        if (t < off) red[t] += red[t + off];
        __syncthreads();
    }
    float inv = 1.f / red[0];
    if (t < SB) coef[((size_t)b * NN + n) * SB + t] = p * inv;
}

// ---------------------------------------------------------------------------
// K3: out[b][n][c] = sum_s X[b][c][s] * coef[b][n][s]
// grid (20 n-tiles of 4, 32 c-tiles of 64, 8 b), block 256 = 64c x 4n
// ---------------------------------------------------------------------------
__global__ __launch_bounds__(256) void k3_out(const float* __restrict__ X,
                                              const float* __restrict__ coef,
                                              float* __restrict__ out) {
    const int t = threadIdx.x;
    const int c = blockIdx.y * 64 + (t & 63);
    const int n = blockIdx.x * 4 + (t >> 6);
    const int b = blockIdx.z;
    const float4* xr = (const float4*)(X + ((size_t)b * NC + c) * SB);
    const float4* cr = (const float4*)(coef + ((size_t)b * NN + n) * SB);
    float acc = 0.f;
    #pragma unroll 7
    for (int i = 0; i < SB / 4; ++i) {
        float4 a = xr[i], w = cr[i];
        acc += a.x * w.x + a.y * w.y + a.z * w.z + a.w * w.w;
    }
    out[((size_t)b * NN + n) * NC + c] = acc;
}

// ---------------------------------------------------------------------------
extern "C" void kernel_launch(void* const* d_in, const int* in_sizes, int n_in,
                              void* d_out, int out_size, void* d_ws, size_t ws_size,
                              hipStream_t stream) {
    const float* X    = (const float*)d_in[0];  // [8][2048][196]
    const float* word = (const float*)d_in[1];  // [80][300]
    const float* W1   = (const float*)d_in[2];  // [1024][2048]
    const float* W2   = (const float*)d_in[3];  // [1024][300]
    const float* W3   = (const float*)d_in[4];  // [1024][1024]
    // d_in[5] = b3, d_in[7] = ba: cancel in softmax (uniform over s) -> unused
    const float* Wa   = (const float*)d_in[6];  // [1][1024]
    float* out = (float*)d_out;

    char* ws = (char*)d_ws;
    float* v    = (float*)ws;                                   // 1024
    float* fwd  = v + ND;                                       // 80*1024
    float* F    = fwd + (size_t)NN * ND;                        // 8*1024*196
    float* coef = F + (size_t)NB * ND * SB;                     // 8*80*196
    size_t f32_bytes = (size_t)(ND + NN * ND + NB * ND * SB + NB * NN * SB) * 4;
    // align 16
    f32_bytes = (f32_bytes + 15) & ~(size_t)15;
    __bf16* W1b = (__bf16*)(ws + f32_bytes);                    // 1024*2048 bf16 (4 MB)
    __bf16* Xt  = W1b + (size_t)ND * NC;                        // 8*196*2048 bf16 (6.4 MB)
    // total ~17.9 MB of d_ws

    hipMemsetAsync(v, 0, ND * sizeof(float), stream);
    kcast_w1<<<dim3((ND * NC) / (256 * 4)), 256, 0, stream>>>(W1, W1b);
    kcast_x <<<dim3(32, 4, NB),             256, 0, stream>>>(X, Xt);
    k0_v    <<<dim3(4, 16),                 256, 0, stream>>>(W3, Wa, v);
    k0_fwd  <<<dim3(NN, 4),                 256, 0, stream>>>(word, W2, fwd);
    k1_mfma <<<dim3(16, 4, NB),             256, 0, stream>>>(Xt, W1b, F);
    k2_coef <<<dim3(NN, NB),                256, 0, stream>>>(F, fwd, v, coef);
    k3_out  <<<dim3(20, 32, NB),            256, 0, stream>>>(X, coef, out);
}

// Round 3
// 222.466 us; speedup vs baseline: 2.7280x; 1.3449x over previous
//
#include <hip/hip_runtime.h>
#include <math.h>

// Problem constants (match reference setup_inputs)
#define SB 196   // spatial s = h*w = 14*14
#define SP 224   // s padded to 7*32 for MFMA K-steps
#define NB 8     // batch
#define NC 2048  // channels
#define ND 1024  // INTER_DIM
#define NN 80    // NUM_CLASSES
#define NW 300   // WORD_DIM

typedef __bf16 v8bf __attribute__((ext_vector_type(8)));
typedef __bf16 v4bf __attribute__((ext_vector_type(4)));
typedef __bf16 v2bf __attribute__((ext_vector_type(2)));
typedef float  f32x4 __attribute__((ext_vector_type(4)));

// ---------------------------------------------------------------------------
// K0a: v[d] = sum_e Wa[e] * W3[e][d]   (Wa @ W3), accumulated via atomics.
// ---------------------------------------------------------------------------
__global__ __launch_bounds__(256) void k0_v(const float* __restrict__ W3,
                                            const float* __restrict__ Wa,
                                            float* __restrict__ v) {
    int d  = blockIdx.x * 256 + threadIdx.x;
    int e0 = blockIdx.y * 64;
    float p = 0.f;
    #pragma unroll 8
    for (int e = e0; e < e0 + 64; ++e) {
        p += Wa[e] * W3[(size_t)e * ND + d];   // coalesced over d
    }
    atomicAdd(&v[d], p);
}

// ---------------------------------------------------------------------------
// K0b: fwd[n][d] = sum_w word[n][w] * W2[d][w]
// ---------------------------------------------------------------------------
__global__ __launch_bounds__(256) void k0_fwd(const float* __restrict__ word,
                                              const float* __restrict__ W2,
                                              float* __restrict__ fwd) {
    __shared__ __align__(16) float lword[NW];
    int n = blockIdx.x;
    int d = blockIdx.y * 256 + threadIdx.x;
    for (int i = threadIdx.x; i < NW; i += 256) lword[i] = word[(size_t)n * NW + i];
    __syncthreads();
    const float4* wr = (const float4*)(W2 + (size_t)d * NW);
    const float4* l4 = (const float4*)lword;
    float acc = 0.f;
    #pragma unroll 5
    for (int i = 0; i < NW / 4; ++i) {
        float4 a = wr[i], b = l4[i];
        acc += a.x * b.x + a.y * b.y + a.z * b.z + a.w * b.w;
    }
    fwd[(size_t)n * ND + d] = acc;
}

// ---------------------------------------------------------------------------
// Cast W1 [1024][2048] fp32 -> bf16, same layout. 2M elems / 4 per thread.
// ---------------------------------------------------------------------------
__global__ __launch_bounds__(256) void kcast_w1(const float* __restrict__ W1,
                                                __bf16* __restrict__ O) {
    size_t i = ((size_t)blockIdx.x * 256 + threadIdx.x) * 4;
    float4 f = *(const float4*)(W1 + i);
    v4bf o;
    o[0] = (__bf16)f.x; o[1] = (__bf16)f.y; o[2] = (__bf16)f.z; o[3] = (__bf16)f.w;
    *(v4bf*)(O + i) = o;
}

// ---------------------------------------------------------------------------
// Cast+transpose X [b][c][s] fp32 -> Xt [b][s][c] bf16 (LDS-tiled 64x64).
// grid (32 c-tiles, 4 s-tiles, 8 b)
// ---------------------------------------------------------------------------
__global__ __launch_bounds__(256) void kcast_x(const float* __restrict__ X,
                                               __bf16* __restrict__ Xt) {
    __shared__ float tile[64][65];   // [c][s], +1 pad
    const int b  = blockIdx.z;
    const int c0 = blockIdx.x * 64;
    const int s0 = blockIdx.y * 64;
    const int t  = threadIdx.x;
    const float* Xb = X + (size_t)b * NC * SB;
    {   // read: coalesced over s
        int ss = t & 63, cbase = t >> 6;
        #pragma unroll
        for (int r = 0; r < 16; ++r) {
            int cc = cbase + 4 * r;
            float val = (s0 + ss < SB) ? Xb[(size_t)(c0 + cc) * SB + s0 + ss] : 0.f;
            tile[cc][ss] = val;
        }
    }
    __syncthreads();
    {   // write: coalesced over c
        int cc = t & 63, sbase = t >> 6;
        #pragma unroll
        for (int r = 0; r < 16; ++r) {
            int ss = sbase + 4 * r;
            if (s0 + ss < SB)
                Xt[((size_t)b * SB + s0 + ss) * NC + c0 + cc] = (__bf16)tile[cc][ss];
        }
    }
}

// ---------------------------------------------------------------------------
// K1 (MFMA): F[b][d][s] = sum_c W1[d][c] * X[b][c][s], bf16 inputs, fp32 out.
// ---------------------------------------------------------------------------
#define PITCH 40
__global__ __launch_bounds__(256) void k1_mfma(const __bf16* __restrict__ Xt,
                                               const __bf16* __restrict__ W1b,
                                               float* __restrict__ F) {
    __shared__ __align__(16) __bf16 lA[64 * PITCH];
    __shared__ __align__(16) __bf16 lB[64 * PITCH];
    const int t    = threadIdx.x;
    const int d0   = blockIdx.x * 64;
    const int s0   = blockIdx.y * 64;
    const int b    = blockIdx.z;
    const int lane = t & 63;
    const int wave = t >> 6;
    const int doff = (wave & 1) * 32;
    const int soff = (wave >> 1) * 32;
    const int quad = lane >> 4;
    const int l16  = lane & 15;

    f32x4 acc[2][2] = {};

    const int rr = t >> 2;
    const int cc = (t & 3) * 8;
    const bool sv = (s0 + rr) < SB;
    const __bf16* Ag = W1b + (size_t)(d0 + rr) * NC + cc;
    const __bf16* Bg = Xt + ((size_t)b * SB + (sv ? (s0 + rr) : 0)) * NC + cc;
    __bf16* lAw = lA + rr * PITCH + cc;
    __bf16* lBw = lB + rr * PITCH + cc;

    const __bf16* rA0 = lA + (doff + l16) * PITCH + quad * 8;
    const __bf16* rA1 = rA0 + 16 * PITCH;
    const __bf16* rB0 = lB + (soff + l16) * PITCH + quad * 8;
    const __bf16* rB1 = rB0 + 16 * PITCH;

    for (int k0 = 0; k0 < NC; k0 += 32) {
        uint4 a = *(const uint4*)(Ag + k0);
        uint4 bv = sv ? *(const uint4*)(Bg + k0) : make_uint4(0u, 0u, 0u, 0u);
        __syncthreads();
        *(uint4*)lAw = a;
        *(uint4*)lBw = bv;
        __syncthreads();
        v8bf a0 = *(const v8bf*)rA0;
        v8bf a1 = *(const v8bf*)rA1;
        v8bf b0 = *(const v8bf*)rB0;
        v8bf b1 = *(const v8bf*)rB1;
        acc[0][0] = __builtin_amdgcn_mfma_f32_16x16x32_bf16(a0, b0, acc[0][0], 0, 0, 0);
        acc[0][1] = __builtin_amdgcn_mfma_f32_16x16x32_bf16(a0, b1, acc[0][1], 0, 0, 0);
        acc[1][0] = __builtin_amdgcn_mfma_f32_16x16x32_bf16(a1, b0, acc[1][0], 0, 0, 0);
        acc[1][1] = __builtin_amdgcn_mfma_f32_16x16x32_bf16(a1, b1, acc[1][1], 0, 0, 0);
    }
    float* Fb = F + (size_t)b * ND * SB;
    #pragma unroll
    for (int i = 0; i < 2; ++i) {
        #pragma unroll
        for (int j = 0; j < 2; ++j) {
            int s = s0 + soff + j * 16 + l16;
            if (s < SB) {
                #pragma unroll
                for (int r = 0; r < 4; ++r) {
                    int d = d0 + doff + i * 16 + quad * 4 + r;
                    Fb[(size_t)d * SB + s] = acc[i][j][r];
                }
            }
        }
    }
}

// ---------------------------------------------------------------------------
// K2: logits l[s] = sum_d v[d] * tanh(F[b][d][s] * fwd[n][d]); softmax over s;
// write split-precision coef hi/lo bf16, s-padded to 224 with zeros.
// One block per (n, b); thread = s.
// ---------------------------------------------------------------------------
__global__ __launch_bounds__(256) void k2_coef(const float* __restrict__ F,
                                               const float* __restrict__ fwd,
                                               const float* __restrict__ v,
                                               __bf16* __restrict__ coefh,
                                               __bf16* __restrict__ coefl) {
    __shared__ float lv[ND];
    __shared__ float lw[ND];
    __shared__ float red[256];
    const int n = blockIdx.x;
    const int b = blockIdx.y;
    const int t = threadIdx.x;
    for (int i = t; i < ND; i += 256) {
        lv[i] = v[i];
        lw[i] = fwd[(size_t)n * ND + i];
    }
    __syncthreads();

    float acc = 0.f;
    const float* Fb = F + (size_t)b * ND * SB;
    if (t < SB) {
        #pragma unroll 8
        for (int d = 0; d < ND; ++d) {
            float x = Fb[(size_t)d * SB + t] * lw[d];
            float e = __expf(2.f * x);
            float r = __builtin_amdgcn_rcpf(e + 1.f);
            acc += lv[d] * (1.f - 2.f * r);
        }
    }
    red[t] = (t < SB) ? acc : -1e30f;
    __syncthreads();
    #pragma unroll
    for (int off = 128; off > 0; off >>= 1) {
        if (t < off) red[t] = fmaxf(red[t], red[t + off]);
        __syncthreads();
    }
    float m = red[0];
    __syncthreads();
    float p = (t < SB) ? __expf(acc - m) : 0.f;
    red[t] = p;
    __syncthreads();
    #pragma unroll
    for (int off = 128; off > 0; off >>= 1) {
        if (t < off) red[t] += red[t + off];
        __syncthreads();
    }
    float inv = 1.f / red[0];
    if (t < SP) {
        float val = (t < SB) ? p * inv : 0.f;
        __bf16 h = (__bf16)val;
        __bf16 l = (__bf16)(val - (float)h);
        size_t base = ((size_t)b * NN + n) * SP + t;
        coefh[base] = h;
        coefl[base] = l;
    }
}

// ---------------------------------------------------------------------------
// Cast X [b][c][s] fp32 -> Xhi/Xlo [b][c][224] bf16 split, zero s-pad.
// Pair-per-thread: 8*2048 rows * 112 pairs = 1,835,008 threads.
// ---------------------------------------------------------------------------
__global__ __launch_bounds__(256) void kcast_xs(const float* __restrict__ X,
                                                __bf16* __restrict__ Xhi,
                                                __bf16* __restrict__ Xlo) {
    unsigned int i = blockIdx.x * 256 + threadIdx.x;   // pair index
    unsigned int row = i / 112;
    int s2 = (int)(i % 112) * 2;
    float x0 = 0.f, x1 = 0.f;
    if (s2 < SB) {   // SB=196 even: pair fully valid or fully pad
        float2 x = *(const float2*)(X + (size_t)row * SB + s2);
        x0 = x.x; x1 = x.y;
    }
    __bf16 h0 = (__bf16)x0, h1 = (__bf16)x1;
    __bf16 l0 = (__bf16)(x0 - (float)h0), l1 = (__bf16)(x1 - (float)h1);
    v2bf hv; hv[0] = h0; hv[1] = h1;
    v2bf lv; lv[0] = l0; lv[1] = l1;
    *(v2bf*)(Xhi + (size_t)row * SP + s2) = hv;
    *(v2bf*)(Xlo + (size_t)row * SP + s2) = lv;
}

// ---------------------------------------------------------------------------
// K3 (MFMA, split precision): out[b][n][c] = sum_s coef[b][n][s] * X[b][c][s]
// A = coef hi/lo [n][224] rows, B = X hi/lo [c][224] rows (both k-contiguous).
// out ~= Ah*Bh + Al*Bh + Ah*Bl  (Al*Bl dropped, ~2^-18).
// grid (32 c-tiles of 64, 8 b), block 256: wave w owns 16 c, 5 m-tiles (80 n).
// ---------------------------------------------------------------------------
__global__ __launch_bounds__(256) void k3_mfma(const __bf16* __restrict__ Xhi,
                                               const __bf16* __restrict__ Xlo,
                                               const __bf16* __restrict__ coefh,
                                               const __bf16* __restrict__ coefl,
                                               float* __restrict__ out) {
    const int t     = threadIdx.x;
    const int wave  = t >> 6;
    const int lane  = t & 63;
    const int quad  = lane >> 4;
    const int l16   = lane & 15;
    const int b     = blockIdx.y;
    const int cbase = blockIdx.x * 64 + wave * 16;

    const __bf16* Bh = Xhi + ((size_t)b * NC + cbase + l16) * SP + quad * 8;
    const __bf16* Bl = Xlo + ((size_t)b * NC + cbase + l16) * SP + quad * 8;
    const __bf16* Ah = coefh + ((size_t)b * NN + l16) * SP + quad * 8;
    const __bf16* Al = coefl + ((size_t)b * NN + l16) * SP + quad * 8;

    f32x4 acc[5] = {};

    #pragma unroll
    for (int k0 = 0; k0 < SP; k0 += 32) {
        v8bf bh = *(const v8bf*)(Bh + k0);
        v8bf bl = *(const v8bf*)(Bl + k0);
        #pragma unroll
        for (int mt = 0; mt < 5; ++mt) {
            v8bf ah = *(const v8bf*)(Ah + (size_t)mt * 16 * SP + k0);
            v8bf al = *(const v8bf*)(Al + (size_t)mt * 16 * SP + k0);
            acc[mt] = __builtin_amdgcn_mfma_f32_16x16x32_bf16(ah, bh, acc[mt], 0, 0, 0);
            acc[mt] = __builtin_amdgcn_mfma_f32_16x16x32_bf16(al, bh, acc[mt], 0, 0, 0);
            acc[mt] = __builtin_amdgcn_mfma_f32_16x16x32_bf16(ah, bl, acc[mt], 0, 0, 0);
        }
    }
    // C[row = mt*16 + quad*4 + r (n), col = l16 (c)]
    #pragma unroll
    for (int mt = 0; mt < 5; ++mt) {
        #pragma unroll
        for (int r = 0; r < 4; ++r) {
            int n = mt * 16 + quad * 4 + r;
            out[((size_t)b * NN + n) * NC + cbase + l16] = acc[mt][r];
        }
    }
}

// ---------------------------------------------------------------------------
extern "C" void kernel_launch(void* const* d_in, const int* in_sizes, int n_in,
                              void* d_out, int out_size, void* d_ws, size_t ws_size,
                              hipStream_t stream) {
    const float* X    = (const float*)d_in[0];  // [8][2048][196]
    const float* word = (const float*)d_in[1];  // [80][300]
    const float* W1   = (const float*)d_in[2];  // [1024][2048]
    const float* W2   = (const float*)d_in[3];  // [1024][300]
    const float* W3   = (const float*)d_in[4];  // [1024][1024]
    // d_in[5] = b3, d_in[7] = ba: cancel in softmax (uniform over s) -> unused
    const float* Wa   = (const float*)d_in[6];  // [1][1024]
    float* out = (float*)d_out;

    char* ws = (char*)d_ws;
    float*  v     = (float*)ws;                          // 1024 f
    float*  fwd   = v + ND;                              // 80*1024 f
    __bf16* coefh = (__bf16*)(fwd + (size_t)NN * ND);    // 8*80*224 bf16
    __bf16* coefl = coefh + (size_t)NB * NN * SP;        // 8*80*224 bf16
    // big region, two phase-disjoint layouts:
    size_t big_off = ((size_t)((char*)(coefl + (size_t)NB * NN * SP) - ws) + 255) & ~(size_t)255;
    char* big = ws + big_off;
    // phase A (kcast_w1..k2): W1b, Xt, F
    __bf16* W1b = (__bf16*)big;                          // 1024*2048 bf16   (4.00 MB)
    __bf16* Xt  = W1b + (size_t)ND * NC;                 // 8*196*2048 bf16  (6.42 MB)
    float*  F   = (float*)(Xt + (size_t)NB * SB * NC);   // 8*1024*196 f32   (6.42 MB)
    // phase B (kcast_xs..k3, overwrites phase A): Xhi, Xlo
    __bf16* Xhi = (__bf16*)big;                          // 8*2048*224 bf16  (7.34 MB)
    __bf16* Xlo = Xhi + (size_t)NB * NC * SP;            // 8*2048*224 bf16  (7.34 MB)
    // peak ws use ~18 MB (same as previous passing round)

    hipMemsetAsync(v, 0, ND * sizeof(float), stream);
    kcast_w1<<<dim3((ND * NC) / (256 * 4)), 256, 0, stream>>>(W1, W1b);
    kcast_x <<<dim3(32, 4, NB),             256, 0, stream>>>(X, Xt);
    k0_v    <<<dim3(4, 16),                 256, 0, stream>>>(W3, Wa, v);
    k0_fwd  <<<dim3(NN, 4),                 256, 0, stream>>>(word, W2, fwd);
    k1_mfma <<<dim3(16, 4, NB),             256, 0, stream>>>(Xt, W1b, F);
    k2_coef <<<dim3(NN, NB),                256, 0, stream>>>(F, fwd, v, coefh, coefl);
    kcast_xs<<<dim3((NB * NC * (SP / 2)) / 256), 256, 0, stream>>>(X, Xhi, Xlo);
    k3_mfma <<<dim3(NC / 64, NB),           256, 0, stream>>>(Xhi, Xlo, coefh, coefl, out);
}

// Round 6
// 211.186 us; speedup vs baseline: 2.8737x; 1.0534x over previous
//
#include <hip/hip_runtime.h>
#include <math.h>

// Problem constants (match reference setup_inputs)
#define SB 196   // spatial s = h*w = 14*14
#define SP 224   // s padded to 7*32 for MFMA K-steps
#define NB 8     // batch
#define NC 2048  // channels
#define ND 1024  // INTER_DIM
#define NN 80    // NUM_CLASSES
#define NW 300   // WORD_DIM

typedef __bf16 v8bf __attribute__((ext_vector_type(8)));
typedef __bf16 v4bf __attribute__((ext_vector_type(4)));
typedef __bf16 v2bf __attribute__((ext_vector_type(2)));
typedef float  f32x4 __attribute__((ext_vector_type(4)));

// ---------------------------------------------------------------------------
// K0a: v[d] = sum_e Wa[e] * W3[e][d]   (Wa @ W3), accumulated via atomics.
// ---------------------------------------------------------------------------
__global__ __launch_bounds__(256) void k0_v(const float* __restrict__ W3,
                                            const float* __restrict__ Wa,
                                            float* __restrict__ v) {
    int d  = blockIdx.x * 256 + threadIdx.x;
    int e0 = blockIdx.y * 64;
    float p = 0.f;
    #pragma unroll 8
    for (int e = e0; e < e0 + 64; ++e) {
        p += Wa[e] * W3[(size_t)e * ND + d];   // coalesced over d
    }
    atomicAdd(&v[d], p);
}

// ---------------------------------------------------------------------------
// K0b: fwd[n][d] = sum_w word[n][w] * W2[d][w]
// ---------------------------------------------------------------------------
__global__ __launch_bounds__(256) void k0_fwd(const float* __restrict__ word,
                                              const float* __restrict__ W2,
                                              float* __restrict__ fwd) {
    __shared__ __align__(16) float lword[NW];
    int n = blockIdx.x;
    int d = blockIdx.y * 256 + threadIdx.x;
    for (int i = threadIdx.x; i < NW; i += 256) lword[i] = word[(size_t)n * NW + i];
    __syncthreads();
    const float4* wr = (const float4*)(W2 + (size_t)d * NW);
    const float4* l4 = (const float4*)lword;
    float acc = 0.f;
    #pragma unroll 5
    for (int i = 0; i < NW / 4; ++i) {
        float4 a = wr[i], b = l4[i];
        acc += a.x * b.x + a.y * b.y + a.z * b.z + a.w * b.w;
    }
    fwd[(size_t)n * ND + d] = acc;
}

// ---------------------------------------------------------------------------
// Cast W1 [1024][2048] fp32 -> bf16, same layout.
// ---------------------------------------------------------------------------
__global__ __launch_bounds__(256) void kcast_w1(const float* __restrict__ W1,
                                                __bf16* __restrict__ O) {
    size_t i = ((size_t)blockIdx.x * 256 + threadIdx.x) * 4;
    float4 f = *(const float4*)(W1 + i);
    v4bf o;
    o[0] = (__bf16)f.x; o[1] = (__bf16)f.y; o[2] = (__bf16)f.z; o[3] = (__bf16)f.w;
    *(v4bf*)(O + i) = o;
}

// ---------------------------------------------------------------------------
// Cast+transpose X [b][c][s] fp32 -> Xt [b][s][c] bf16 (LDS-tiled 64x64).
// grid (32 c-tiles, 4 s-tiles, 8 b)
// ---------------------------------------------------------------------------
__global__ __launch_bounds__(256) void kcast_x(const float* __restrict__ X,
                                               __bf16* __restrict__ Xt) {
    __shared__ float tile[64][65];   // [c][s], +1 pad
    const int b  = blockIdx.z;
    const int c0 = blockIdx.x * 64;
    const int s0 = blockIdx.y * 64;
    const int t  = threadIdx.x;
    const float* Xb = X + (size_t)b * NC * SB;
    {   // read: coalesced over s
        int ss = t & 63, cbase = t >> 6;
        #pragma unroll
        for (int r = 0; r < 16; ++r) {
            int cc = cbase + 4 * r;
            float val = (s0 + ss < SB) ? Xb[(size_t)(c0 + cc) * SB + s0 + ss] : 0.f;
            tile[cc][ss] = val;
        }
    }
    __syncthreads();
    {   // write: coalesced over c
        int cc = t & 63, sbase = t >> 6;
        #pragma unroll
        for (int r = 0; r < 16; ++r) {
            int ss = sbase + 4 * r;
            if (s0 + ss < SB)
                Xt[((size_t)b * SB + s0 + ss) * NC + c0 + cc] = (__bf16)tile[cc][ss];
        }
    }
}

// ---------------------------------------------------------------------------
// K1 (MFMA): F[b][d][s] = sum_c W1[d][c] * X[b][c][s], bf16 inputs, fp32 out.
// Block tile 64d x 64s, 4 waves each own a 32x32 quadrant (2x2 16x16 frags).
// K-step 32. A = W1b [d][c] rows; B = Xt [s][c] rows (both c-contiguous).
// grid (16 d-tiles, 4 s-tiles, 8 b), block 256.  (exact R3 version)
// ---------------------------------------------------------------------------
#define PITCH 40
__global__ __launch_bounds__(256) void k1_mfma(const __bf16* __restrict__ Xt,
                                               const __bf16* __restrict__ W1b,
                                               float* __restrict__ F) {
    __shared__ __align__(16) __bf16 lA[64 * PITCH];
    __shared__ __align__(16) __bf16 lB[64 * PITCH];
    const int t    = threadIdx.x;
    const int d0   = blockIdx.x * 64;
    const int s0   = blockIdx.y * 64;
    const int b    = blockIdx.z;
    const int lane = t & 63;
    const int wave = t >> 6;
    const int doff = (wave & 1) * 32;
    const int soff = (wave >> 1) * 32;
    const int quad = lane >> 4;
    const int l16  = lane & 15;

    f32x4 acc[2][2] = {};

    const int rr = t >> 2;
    const int cc = (t & 3) * 8;
    const bool sv = (s0 + rr) < SB;
    const __bf16* Ag = W1b + (size_t)(d0 + rr) * NC + cc;
    const __bf16* Bg = Xt + ((size_t)b * SB + (sv ? (s0 + rr) : 0)) * NC + cc;
    __bf16* lAw = lA + rr * PITCH + cc;
    __bf16* lBw = lB + rr * PITCH + cc;

    const __bf16* rA0 = lA + (doff + l16) * PITCH + quad * 8;
    const __bf16* rA1 = rA0 + 16 * PITCH;
    const __bf16* rB0 = lB + (soff + l16) * PITCH + quad * 8;
    const __bf16* rB1 = rB0 + 16 * PITCH;

    for (int k0 = 0; k0 < NC; k0 += 32) {
        uint4 a = *(const uint4*)(Ag + k0);
        uint4 bv = sv ? *(const uint4*)(Bg + k0) : make_uint4(0u, 0u, 0u, 0u);
        __syncthreads();
        *(uint4*)lAw = a;
        *(uint4*)lBw = bv;
        __syncthreads();
        v8bf a0 = *(const v8bf*)rA0;
        v8bf a1 = *(const v8bf*)rA1;
        v8bf b0 = *(const v8bf*)rB0;
        v8bf b1 = *(const v8bf*)rB1;
        acc[0][0] = __builtin_amdgcn_mfma_f32_16x16x32_bf16(a0, b0, acc[0][0], 0, 0, 0);
        acc[0][1] = __builtin_amdgcn_mfma_f32_16x16x32_bf16(a0, b1, acc[0][1], 0, 0, 0);
        acc[1][0] = __builtin_amdgcn_mfma_f32_16x16x32_bf16(a1, b0, acc[1][0], 0, 0, 0);
        acc[1][1] = __builtin_amdgcn_mfma_f32_16x16x32_bf16(a1, b1, acc[1][1], 0, 0, 0);
    }
    float* Fb = F + (size_t)b * ND * SB;
    #pragma unroll
    for (int i = 0; i < 2; ++i) {
        #pragma unroll
        for (int j = 0; j < 2; ++j) {
            int s = s0 + soff + j * 16 + l16;
            if (s < SB) {
                #pragma unroll
                for (int r = 0; r < 4; ++r) {
                    int d = d0 + doff + i * 16 + quad * 4 + r;
                    Fb[(size_t)d * SB + s] = acc[i][j][r];
                }
            }
        }
    }
}

// ---------------------------------------------------------------------------
// K2: logits l[s] = sum_d v[d] * tanh(F[b][d][s] * fwd[n][d]); softmax over s;
// write split bf16 coef (SP-padded). One block per (n, b).
// Block = 1024 threads = 4 d-chunks x 256 s-threads (in-block d-parallelism:
// R3 version ran 1 chunk serially over d=1024 at 22% occupancy).
// Math is identical to the R3-proven version.
// ---------------------------------------------------------------------------
__global__ __launch_bounds__(1024) void k2_coef(const float* __restrict__ F,
                                                const float* __restrict__ fwd,
                                                const float* __restrict__ v,
                                                __bf16* __restrict__ coefh,
                                                __bf16* __restrict__ coefl) {
    __shared__ float lv[ND];
    __shared__ float lw[ND];
    __shared__ float partial[3][256];
    __shared__ float red[256];
    const int n   = blockIdx.x;
    const int b   = blockIdx.y;
    const int t   = threadIdx.x;
    const int s   = t & 255;
    const int chk = t >> 8;          // 0..3, each owns 256 d's
    lv[t] = v[t];
    lw[t] = fwd[(size_t)n * ND + t];
    __syncthreads();

    float acc = 0.f;
    const float* Fb = F + (size_t)b * ND * SB;
    if (s < SB) {
        const int dbase = chk * 256;
        #pragma unroll 8
        for (int dd = 0; dd < 256; ++dd) {
            int d = dbase + dd;
            float x = Fb[(size_t)d * SB + s] * lw[d];
            float e = __expf(2.f * x);
            float r = __builtin_amdgcn_rcpf(e + 1.f);
            acc += lv[d] * (1.f - 2.f * r);
        }
    }
    if (chk > 0) partial[chk - 1][s] = acc;
    __syncthreads();
    if (chk == 0) {
        acc += partial[0][s] + partial[1][s] + partial[2][s];
        red[s] = (s < SB) ? acc : -1e30f;
    }
    __syncthreads();
    #pragma unroll
    for (int off = 128; off > 0; off >>= 1) {
        if (chk == 0 && s < off) red[s] = fmaxf(red[s], red[s + off]);
        __syncthreads();
    }
    float m = red[0];
    __syncthreads();
    float p = (chk == 0 && s < SB) ? __expf(acc - m) : 0.f;
    if (chk == 0) red[s] = p;
    __syncthreads();
    #pragma unroll
    for (int off = 128; off > 0; off >>= 1) {
        if (chk == 0 && s < off) red[s] += red[s + off];
        __syncthreads();
    }
    if (chk == 0 && s < SP) {
        float inv = 1.f / red[0];
        float val = (s < SB) ? p * inv : 0.f;
        __bf16 h = (__bf16)val;
        __bf16 l = (__bf16)(val - (float)h);
        size_t base = ((size_t)b * NN + n) * SP + s;
        coefh[base] = h;
        coefl[base] = l;
    }
}

// ---------------------------------------------------------------------------
// Cast X [b][c][s] fp32 -> Xhi/Xlo [b][c][224] bf16 split, zero s-pad.
// ---------------------------------------------------------------------------
__global__ __launch_bounds__(256) void kcast_xs(const float* __restrict__ X,
                                                __bf16* __restrict__ Xhi,
                                                __bf16* __restrict__ Xlo) {
    unsigned int i = blockIdx.x * 256 + threadIdx.x;   // pair index
    unsigned int row = i / 112;
    int s2 = (int)(i % 112) * 2;
    float x0 = 0.f, x1 = 0.f;
    if (s2 < SB) {
        float2 x = *(const float2*)(X + (size_t)row * SB + s2);
        x0 = x.x; x1 = x.y;
    }
    __bf16 h0 = (__bf16)x0, h1 = (__bf16)x1;
    __bf16 l0 = (__bf16)(x0 - (float)h0), l1 = (__bf16)(x1 - (float)h1);
    v2bf hv; hv[0] = h0; hv[1] = h1;
    v2bf lv; lv[0] = l0; lv[1] = l1;
    *(v2bf*)(Xhi + (size_t)row * SP + s2) = hv;
    *(v2bf*)(Xlo + (size_t)row * SP + s2) = lv;
}

// ---------------------------------------------------------------------------
// K3 (MFMA, split precision): out[b][n][c] = sum_s coef[b][n][s] * X[b][c][s]
// out ~= Ah*Bh + Al*Bh + Ah*Bl. grid (32 c-tiles, 8 b), block 256.
// ---------------------------------------------------------------------------
__global__ __launch_bounds__(256) void k3_mfma(const __bf16* __restrict__ Xhi,
                                               const __bf16* __restrict__ Xlo,
                                               const __bf16* __restrict__ coefh,
                                               const __bf16* __restrict__ coefl,
                                               float* __restrict__ out) {
    const int t     = threadIdx.x;
    const int wave  = t >> 6;
    const int lane  = t & 63;
    const int quad  = lane >> 4;
    const int l16   = lane & 15;
    const int b     = blockIdx.y;
    const int cbase = blockIdx.x * 64 + wave * 16;

    const __bf16* Bh = Xhi + ((size_t)b * NC + cbase + l16) * SP + quad * 8;
    const __bf16* Bl = Xlo + ((size_t)b * NC + cbase + l16) * SP + quad * 8;
    const __bf16* Ah = coefh + ((size_t)b * NN + l16) * SP + quad * 8;
    const __bf16* Al = coefl + ((size_t)b * NN + l16) * SP + quad * 8;

    f32x4 acc[5] = {};

    #pragma unroll
    for (int k0 = 0; k0 < SP; k0 += 32) {
        v8bf bh = *(const v8bf*)(Bh + k0);
        v8bf bl = *(const v8bf*)(Bl + k0);
        #pragma unroll
        for (int mt = 0; mt < 5; ++mt) {
            v8bf ah = *(const v8bf*)(Ah + (size_t)mt * 16 * SP + k0);
            v8bf al = *(const v8bf*)(Al + (size_t)mt * 16 * SP + k0);
            acc[mt] = __builtin_amdgcn_mfma_f32_16x16x32_bf16(ah, bh, acc[mt], 0, 0, 0);
            acc[mt] = __builtin_amdgcn_mfma_f32_16x16x32_bf16(al, bh, acc[mt], 0, 0, 0);
            acc[mt] = __builtin_amdgcn_mfma_f32_16x16x32_bf16(ah, bl, acc[mt], 0, 0, 0);
        }
    }
    #pragma unroll
    for (int mt = 0; mt < 5; ++mt) {
        #pragma unroll
        for (int r = 0; r < 4; ++r) {
            int n = mt * 16 + quad * 4 + r;
            out[((size_t)b * NN + n) * NC + cbase + l16] = acc[mt][r];
        }
    }
}

// ---------------------------------------------------------------------------
// Workspace layout: exact R3 layout (known-good), peak 17,944,576 B.
// ---------------------------------------------------------------------------
extern "C" void kernel_launch(void* const* d_in, const int* in_sizes, int n_in,
                              void* d_out, int out_size, void* d_ws, size_t ws_size,
                              hipStream_t stream) {
    const float* X    = (const float*)d_in[0];  // [8][2048][196]
    const float* word = (const float*)d_in[1];  // [80][300]
    const float* W1   = (const float*)d_in[2];  // [1024][2048]
    const float* W2   = (const float*)d_in[3];  // [1024][300]
    const float* W3   = (const float*)d_in[4];  // [1024][1024]
    // d_in[5] = b3, d_in[7] = ba: cancel in softmax (uniform over s) -> unused
    const float* Wa   = (const float*)d_in[6];  // [1][1024]
    float* out = (float*)d_out;

    char* ws = (char*)d_ws;
    float*  v     = (float*)ws;                             // 1024 f
    float*  fwd   = v + ND;                                 // 80*1024 f
    __bf16* coefh = (__bf16*)(fwd + (size_t)NN * ND);       // 8*80*224 bf16
    __bf16* coefl = coefh + (size_t)NB * NN * SP;           // 8*80*224 bf16
    size_t big_off = ((size_t)((char*)(coefl + (size_t)NB * NN * SP) - ws) + 255) & ~(size_t)255;
    char* big = ws + big_off;
    // phase A (kcast_w1..k2): W1b, Xt, F
    __bf16* W1b = (__bf16*)big;                             // 4.00 MB
    __bf16* Xt  = W1b + (size_t)ND * NC;                    // 6.42 MB
    float*  F   = (float*)(Xt + (size_t)NB * SB * NC);      // 6.42 MB
    // phase B (kcast_xs..k3, overwrites phase A after k2): Xhi, Xlo
    __bf16* Xhi = (__bf16*)big;                             // 7.34 MB
    __bf16* Xlo = Xhi + (size_t)NB * NC * SP;               // 7.34 MB

    hipMemsetAsync(v, 0, ND * sizeof(float), stream);
    k0_v    <<<dim3(4, 16),                 256, 0, stream>>>(W3, Wa, v);
    k0_fwd  <<<dim3(NN, 4),                 256, 0, stream>>>(word, W2, fwd);
    kcast_w1<<<dim3((ND * NC) / (256 * 4)), 256, 0, stream>>>(W1, W1b);
    kcast_x <<<dim3(32, 4, NB),             256, 0, stream>>>(X, Xt);
    k1_mfma <<<dim3(16, 4, NB),             256, 0, stream>>>(Xt, W1b, F);
    k2_coef <<<dim3(NN, NB),               1024, 0, stream>>>(F, fwd, v, coefh, coefl);
    kcast_xs<<<dim3((NB * NC * (SP / 2)) / 256), 256, 0, stream>>>(X, Xhi, Xlo);
    k3_mfma <<<dim3(NC / 64, NB),           256, 0, stream>>>(Xhi, Xlo, coefh, coefl, out);
}

// Round 7
// 198.914 us; speedup vs baseline: 3.0510x; 1.0617x over previous
//
#include <hip/hip_runtime.h>
#include <math.h>

// Problem constants (match reference setup_inputs)
#define SB 196   // spatial s = h*w = 14*14
#define SP 224   // s padded to 7*32 for MFMA K-steps
#define NB 8     // batch
#define NC 2048  // channels
#define ND 1024  // INTER_DIM
#define NN 80    // NUM_CLASSES
#define NW 300   // WORD_DIM
#define CH 4     // d-chunks in k2a
#define DCH (ND / CH)

typedef __bf16 v8bf __attribute__((ext_vector_type(8)));
typedef __bf16 v4bf __attribute__((ext_vector_type(4)));
typedef __bf16 v2bf __attribute__((ext_vector_type(2)));
typedef float  f32x4 __attribute__((ext_vector_type(4)));

// ---------------------------------------------------------------------------
// K0a: v[d] = sum_e Wa[e] * W3[e][d]   (Wa @ W3), accumulated via atomics.
// ---------------------------------------------------------------------------
__global__ __launch_bounds__(256) void k0_v(const float* __restrict__ W3,
                                            const float* __restrict__ Wa,
                                            float* __restrict__ v) {
    int d  = blockIdx.x * 256 + threadIdx.x;
    int e0 = blockIdx.y * 64;
    float p = 0.f;
    #pragma unroll 8
    for (int e = e0; e < e0 + 64; ++e) {
        p += Wa[e] * W3[(size_t)e * ND + d];   // coalesced over d
    }
    atomicAdd(&v[d], p);
}

// ---------------------------------------------------------------------------
// K0b: fwd[n][d] = sum_w word[n][w] * W2[d][w]; emits
//   wpack[n][d] = { 2*log2(e)*fwd, -2*v[d] }
// k2a computes logit' = sum_d wy / (1 + 2^(F*wx)), which equals the reference
// logit minus the s-uniform constant sum(v) (cancels in softmax over s).
// Must run after k0_v (reads v). grid (80, 4), block 256.
// ---------------------------------------------------------------------------
__global__ __launch_bounds__(256) void k0_fwd(const float* __restrict__ word,
                                              const float* __restrict__ W2,
                                              const float* __restrict__ v,
                                              float2* __restrict__ wpack) {
    __shared__ __align__(16) float lword[NW];
    int n = blockIdx.x;
    int d = blockIdx.y * 256 + threadIdx.x;
    for (int i = threadIdx.x; i < NW; i += 256) lword[i] = word[(size_t)n * NW + i];
    __syncthreads();
    const float4* wr = (const float4*)(W2 + (size_t)d * NW);
    const float4* l4 = (const float4*)lword;
    float acc = 0.f;
    #pragma unroll 5
    for (int i = 0; i < NW / 4; ++i) {
        float4 a = wr[i], b = l4[i];
        acc += a.x * b.x + a.y * b.y + a.z * b.z + a.w * b.w;
    }
    float2 o;
    o.x = 2.8853900817779268f * acc;   // 2*log2(e) * fwd[n][d]
    o.y = -2.f * v[d];
    wpack[(size_t)n * ND + d] = o;
}

// ---------------------------------------------------------------------------
// Cast W1 [1024][2048] fp32 -> bf16, same layout.
// ---------------------------------------------------------------------------
__global__ __launch_bounds__(256) void kcast_w1(const float* __restrict__ W1,
                                                __bf16* __restrict__ O) {
    size_t i = ((size_t)blockIdx.x * 256 + threadIdx.x) * 4;
    float4 f = *(const float4*)(W1 + i);
    v4bf o;
    o[0] = (__bf16)f.x; o[1] = (__bf16)f.y; o[2] = (__bf16)f.z; o[3] = (__bf16)f.w;
    *(v4bf*)(O + i) = o;
}

// ---------------------------------------------------------------------------
// Cast+transpose X [b][c][s] fp32 -> Xt [b][s][c] bf16 (LDS-tiled 64x64).
// grid (32 c-tiles, 4 s-tiles, 8 b)
// ---------------------------------------------------------------------------
__global__ __launch_bounds__(256) void kcast_x(const float* __restrict__ X,
                                               __bf16* __restrict__ Xt) {
    __shared__ float tile[64][65];   // [c][s], +1 pad
    const int b  = blockIdx.z;
    const int c0 = blockIdx.x * 64;
    const int s0 = blockIdx.y * 64;
    const int t  = threadIdx.x;
    const float* Xb = X + (size_t)b * NC * SB;
    {   // read: coalesced over s
        int ss = t & 63, cbase = t >> 6;
        #pragma unroll
        for (int r = 0; r < 16; ++r) {
            int cc = cbase + 4 * r;
            float val = (s0 + ss < SB) ? Xb[(size_t)(c0 + cc) * SB + s0 + ss] : 0.f;
            tile[cc][ss] = val;
        }
    }
    __syncthreads();
    {   // write: coalesced over c
        int cc = t & 63, sbase = t >> 6;
        #pragma unroll
        for (int r = 0; r < 16; ++r) {
            int ss = sbase + 4 * r;
            if (s0 + ss < SB)
                Xt[((size_t)b * SB + s0 + ss) * NC + c0 + cc] = (__bf16)tile[cc][ss];
        }
    }
}

// ---------------------------------------------------------------------------
// K1 (MFMA): F[b][d][s] = sum_c W1[d][c] * X[b][c][s], bf16 inputs, fp32 out.
// Block tile 64d x 64s, 4 waves each own a 32x32 quadrant (2x2 16x16 frags).
// K-step 32. grid (16 d-tiles, 4 s-tiles, 8 b), block 256.
// EXACT R3/R6-proven version — do not touch this round (bug isolation).
// ---------------------------------------------------------------------------
#define PITCH 40
__global__ __launch_bounds__(256) void k1_mfma(const __bf16* __restrict__ Xt,
                                               const __bf16* __restrict__ W1b,
                                               float* __restrict__ F) {
    __shared__ __align__(16) __bf16 lA[64 * PITCH];
    __shared__ __align__(16) __bf16 lB[64 * PITCH];
    const int t    = threadIdx.x;
    const int d0   = blockIdx.x * 64;
    const int s0   = blockIdx.y * 64;
    const int b    = blockIdx.z;
    const int lane = t & 63;
    const int wave = t >> 6;
    const int doff = (wave & 1) * 32;
    const int soff = (wave >> 1) * 32;
    const int quad = lane >> 4;
    const int l16  = lane & 15;

    f32x4 acc[2][2] = {};

    const int rr = t >> 2;
    const int cc = (t & 3) * 8;
    const bool sv = (s0 + rr) < SB;
    const __bf16* Ag = W1b + (size_t)(d0 + rr) * NC + cc;
    const __bf16* Bg = Xt + ((size_t)b * SB + (sv ? (s0 + rr) : 0)) * NC + cc;
    __bf16* lAw = lA + rr * PITCH + cc;
    __bf16* lBw = lB + rr * PITCH + cc;

    const __bf16* rA0 = lA + (doff + l16) * PITCH + quad * 8;
    const __bf16* rA1 = rA0 + 16 * PITCH;
    const __bf16* rB0 = lB + (soff + l16) * PITCH + quad * 8;
    const __bf16* rB1 = rB0 + 16 * PITCH;

    for (int k0 = 0; k0 < NC; k0 += 32) {
        uint4 a = *(const uint4*)(Ag + k0);
        uint4 bv = sv ? *(const uint4*)(Bg + k0) : make_uint4(0u, 0u, 0u, 0u);
        __syncthreads();
        *(uint4*)lAw = a;
        *(uint4*)lBw = bv;
        __syncthreads();
        v8bf a0 = *(const v8bf*)rA0;
        v8bf a1 = *(const v8bf*)rA1;
        v8bf b0 = *(const v8bf*)rB0;
        v8bf b1 = *(const v8bf*)rB1;
        acc[0][0] = __builtin_amdgcn_mfma_f32_16x16x32_bf16(a0, b0, acc[0][0], 0, 0, 0);
        acc[0][1] = __builtin_amdgcn_mfma_f32_16x16x32_bf16(a0, b1, acc[0][1], 0, 0, 0);
        acc[1][0] = __builtin_amdgcn_mfma_f32_16x16x32_bf16(a1, b0, acc[1][0], 0, 0, 0);
        acc[1][1] = __builtin_amdgcn_mfma_f32_16x16x32_bf16(a1, b1, acc[1][1], 0, 0, 0);
    }
    float* Fb = F + (size_t)b * ND * SB;
    #pragma unroll
    for (int i = 0; i < 2; ++i) {
        #pragma unroll
        for (int j = 0; j < 2; ++j) {
            int s = s0 + soff + j * 16 + l16;
            if (s < SB) {
                #pragma unroll
                for (int r = 0; r < 4; ++r) {
                    int d = d0 + doff + i * 16 + quad * 4 + r;
                    Fb[(size_t)d * SB + s] = acc[i][j][r];
                }
            }
        }
    }
}

// ---------------------------------------------------------------------------
// K2a: partial logits. part[ch][b][n][t] = sum_{d in chunk} wy/(1 + 2^(F*wx))
// grid (80 n, 8 b, 4 ch) = 2560 blocks (exactly 10/CU), block 256 (thread=s).
// wpack[n][d] is wave-uniform -> scalar s_loads; 3 VALU + 2 trans per iter.
// ---------------------------------------------------------------------------
__global__ __launch_bounds__(256) void k2a(const float* __restrict__ F,
                                           const float2* __restrict__ wpack,
                                           float* __restrict__ part) {
    const int n  = blockIdx.x;
    const int b  = blockIdx.y;
    const int ch = blockIdx.z;
    const int t  = threadIdx.x;
    const int sc = (t < SB) ? t : (SB - 1);   // clamp: stay in-bounds
    const float*  Fp = F + ((size_t)b * ND + ch * DCH) * SB + sc;
    const float2* wp = wpack + (size_t)n * ND + ch * DCH;
    float acc = 0.f;
    #pragma unroll 8
    for (int d = 0; d < DCH; ++d) {
        float2 w = wp[d];                              // wave-uniform -> s_load
        float x = Fp[(size_t)d * SB] * w.x;
        float e = __builtin_amdgcn_exp2f(x);           // v_exp_f32
        float r = __builtin_amdgcn_rcpf(1.f + e);      // v_rcp_f32
        acc = fmaf(w.y, r, acc);
    }
    part[(((size_t)ch * NB + b) * NN + n) * 256 + t] = acc;
}

// ---------------------------------------------------------------------------
// K2b: sum 4 chunks, softmax over s, write split bf16 coef (SP-padded).
// grid (80 n, 8 b), block 256.
// ---------------------------------------------------------------------------
__global__ __launch_bounds__(256) void k2b(const float* __restrict__ part,
                                           __bf16* __restrict__ coefh,
                                           __bf16* __restrict__ coefl) {
    __shared__ float red[256];
    const int n = blockIdx.x;
    const int b = blockIdx.y;
    const int t = threadIdx.x;
    float acc = 0.f;
    #pragma unroll
    for (int ch = 0; ch < CH; ++ch)
        acc += part[(((size_t)ch * NB + b) * NN + n) * 256 + t];

    red[t] = (t < SB) ? acc : -1e30f;
    __syncthreads();
    #pragma unroll
    for (int off = 128; off > 0; off >>= 1) {
        if (t < off) red[t] = fmaxf(red[t], red[t + off]);
        __syncthreads();
    }
    float m = red[0];
    __syncthreads();
    float p = (t < SB) ? __expf(acc - m) : 0.f;
    red[t] = p;
    __syncthreads();
    #pragma unroll
    for (int off = 128; off > 0; off >>= 1) {
        if (t < off) red[t] += red[t + off];
        __syncthreads();
    }
    float inv = 1.f / red[0];
    if (t < SP) {
        float val = (t < SB) ? p * inv : 0.f;
        __bf16 h = (__bf16)val;
        __bf16 l = (__bf16)(val - (float)h);
        size_t base = ((size_t)b * NN + n) * SP + t;
        coefh[base] = h;
        coefl[base] = l;
    }
}

// ---------------------------------------------------------------------------
// Cast X [b][c][s] fp32 -> Xhi/Xlo [b][c][224] bf16 split, zero s-pad.
// ---------------------------------------------------------------------------
__global__ __launch_bounds__(256) void kcast_xs(const float* __restrict__ X,
                                                __bf16* __restrict__ Xhi,
                                                __bf16* __restrict__ Xlo) {
    unsigned int i = blockIdx.x * 256 + threadIdx.x;   // pair index
    unsigned int row = i / 112;
    int s2 = (int)(i % 112) * 2;
    float x0 = 0.f, x1 = 0.f;
    if (s2 < SB) {
        float2 x = *(const float2*)(X + (size_t)row * SB + s2);
        x0 = x.x; x1 = x.y;
    }
    __bf16 h0 = (__bf16)x0, h1 = (__bf16)x1;
    __bf16 l0 = (__bf16)(x0 - (float)h0), l1 = (__bf16)(x1 - (float)h1);
    v2bf hv; hv[0] = h0; hv[1] = h1;
    v2bf lv; lv[0] = l0; lv[1] = l1;
    *(v2bf*)(Xhi + (size_t)row * SP + s2) = hv;
    *(v2bf*)(Xlo + (size_t)row * SP + s2) = lv;
}

// ---------------------------------------------------------------------------
// K3 (MFMA, split precision): out[b][n][c] = sum_s coef[b][n][s] * X[b][c][s]
// out ~= Ah*Bh + Al*Bh + Ah*Bl. grid (32 c-tiles, 8 b), block 256.
// ---------------------------------------------------------------------------
__global__ __launch_bounds__(256) void k3_mfma(const __bf16* __restrict__ Xhi,
                                               const __bf16* __restrict__ Xlo,
                                               const __bf16* __restrict__ coefh,
                                               const __bf16* __restrict__ coefl,
                                               float* __restrict__ out) {
    const int t     = threadIdx.x;
    const int wave  = t >> 6;
    const int lane  = t & 63;
    const int quad  = lane >> 4;
    const int l16   = lane & 15;
    const int b     = blockIdx.y;
    const int cbase = blockIdx.x * 64 + wave * 16;

    const __bf16* Bh = Xhi + ((size_t)b * NC + cbase + l16) * SP + quad * 8;
    const __bf16* Bl = Xlo + ((size_t)b * NC + cbase + l16) * SP + quad * 8;
    const __bf16* Ah = coefh + ((size_t)b * NN + l16) * SP + quad * 8;
    const __bf16* Al = coefl + ((size_t)b * NN + l16) * SP + quad * 8;

    f32x4 acc[5] = {};

    #pragma unroll
    for (int k0 = 0; k0 < SP; k0 += 32) {
        v8bf bh = *(const v8bf*)(Bh + k0);
        v8bf bl = *(const v8bf*)(Bl + k0);
        #pragma unroll
        for (int mt = 0; mt < 5; ++mt) {
            v8bf ah = *(const v8bf*)(Ah + (size_t)mt * 16 * SP + k0);
            v8bf al = *(const v8bf*)(Al + (size_t)mt * 16 * SP + k0);
            acc[mt] = __builtin_amdgcn_mfma_f32_16x16x32_bf16(ah, bh, acc[mt], 0, 0, 0);
            acc[mt] = __builtin_amdgcn_mfma_f32_16x16x32_bf16(al, bh, acc[mt], 0, 0, 0);
            acc[mt] = __builtin_amdgcn_mfma_f32_16x16x32_bf16(ah, bl, acc[mt], 0, 0, 0);
        }
    }
    #pragma unroll
    for (int mt = 0; mt < 5; ++mt) {
        #pragma unroll
        for (int r = 0; r < 4; ++r) {
            int n = mt * 16 + quad * 4 + r;
            out[((size_t)b * NN + n) * NC + cbase + l16] = acc[mt][r];
        }
    }
}

// ---------------------------------------------------------------------------
// Workspace layout (no aliasing for part/wpack — dedicated regions):
//   front: v(4K) | wpack(640K) | part(2.56M) | coefh(280K) | coefl(280K)
//        = 3,854,336 B
//   big  : phase A = W1b(4M) | Xt(6.42M) | F(6.42M)   -> peak 20,893,696 B
//          phase B = Xhi | Xlo (14.68M, aliases big after k2a done)
// R5 falsified the ws-overflow theory (R3-sized layout still failed), so the
// extra ~3 MB over R3's footprint is considered safe.
// ---------------------------------------------------------------------------
extern "C" void kernel_launch(void* const* d_in, const int* in_sizes, int n_in,
                              void* d_out, int out_size, void* d_ws, size_t ws_size,
                              hipStream_t stream) {
    const float* X    = (const float*)d_in[0];  // [8][2048][196]
    const float* word = (const float*)d_in[1];  // [80][300]
    const float* W1   = (const float*)d_in[2];  // [1024][2048]
    const float* W2   = (const float*)d_in[3];  // [1024][300]
    const float* W3   = (const float*)d_in[4];  // [1024][1024]
    // d_in[5] = b3, d_in[7] = ba: cancel in softmax (uniform over s) -> unused
    const float* Wa   = (const float*)d_in[6];  // [1][1024]
    float* out = (float*)d_out;

    char* ws = (char*)d_ws;
    float*  v     = (float*)ws;                             // 1024 f
    float2* wpack = (float2*)(v + ND);                      // 80*1024 float2
    float*  part  = (float*)(wpack + (size_t)NN * ND);      // 4*8*80*256 f
    __bf16* coefh = (__bf16*)(part + (size_t)CH * NB * NN * 256);
    __bf16* coefl = coefh + (size_t)NB * NN * SP;
    size_t big_off = ((size_t)((char*)(coefl + (size_t)NB * NN * SP) - ws) + 255) & ~(size_t)255;
    char* big = ws + big_off;
    // phase A (kcast_w1..k2a): W1b, Xt, F
    __bf16* W1b = (__bf16*)big;                             // 4.00 MB
    __bf16* Xt  = W1b + (size_t)ND * NC;                    // 6.42 MB
    float*  F   = (float*)(Xt + (size_t)NB * SB * NC);      // 6.42 MB
    // phase B (kcast_xs..k3, overwrites phase A after k2a): Xhi, Xlo
    __bf16* Xhi = (__bf16*)big;                             // 7.34 MB
    __bf16* Xlo = Xhi + (size_t)NB * NC * SP;               // 7.34 MB

    hipMemsetAsync(v, 0, ND * sizeof(float), stream);
    k0_v    <<<dim3(4, 16),                 256, 0, stream>>>(W3, Wa, v);
    k0_fwd  <<<dim3(NN, 4),                 256, 0, stream>>>(word, W2, v, wpack);
    kcast_w1<<<dim3((ND * NC) / (256 * 4)), 256, 0, stream>>>(W1, W1b);
    kcast_x <<<dim3(32, 4, NB),             256, 0, stream>>>(X, Xt);
    k1_mfma <<<dim3(16, 4, NB),             256, 0, stream>>>(Xt, W1b, F);
    k2a     <<<dim3(NN, NB, CH),            256, 0, stream>>>(F, wpack, part);
    k2b     <<<dim3(NN, NB),                256, 0, stream>>>(part, coefh, coefl);
    kcast_xs<<<dim3((NB * NC * (SP / 2)) / 256), 256, 0, stream>>>(X, Xhi, Xlo);
    k3_mfma <<<dim3(NC / 64, NB),           256, 0, stream>>>(Xhi, Xlo, coefh, coefl, out);
}

// Round 8
// 192.532 us; speedup vs baseline: 3.1522x; 1.0331x over previous
//
#include <hip/hip_runtime.h>
#include <math.h>

// Problem constants (match reference setup_inputs)
#define SB 196   // spatial s = h*w = 14*14
#define SP 224   // s padded to 7*32 for MFMA K-steps
#define NB 8     // batch
#define NC 2048  // channels
#define ND 1024  // INTER_DIM
#define NN 80    // NUM_CLASSES
#define NW 300   // WORD_DIM
#define CH 4     // d-chunks in k2a
#define DCH (ND / CH)

typedef __bf16 v8bf __attribute__((ext_vector_type(8)));
typedef __bf16 v4bf __attribute__((ext_vector_type(4)));
typedef __bf16 v2bf __attribute__((ext_vector_type(2)));
typedef float  f32x4 __attribute__((ext_vector_type(4)));

// ---------------------------------------------------------------------------
// K0a: v[d] = sum_e Wa[e] * W3[e][d]   (Wa @ W3), accumulated via atomics.
// ---------------------------------------------------------------------------
__global__ __launch_bounds__(256) void k0_v(const float* __restrict__ W3,
                                            const float* __restrict__ Wa,
                                            float* __restrict__ v) {
    int d  = blockIdx.x * 256 + threadIdx.x;
    int e0 = blockIdx.y * 64;
    float p = 0.f;
    #pragma unroll 8
    for (int e = e0; e < e0 + 64; ++e) {
        p += Wa[e] * W3[(size_t)e * ND + d];   // coalesced over d
    }
    atomicAdd(&v[d], p);
}

// ---------------------------------------------------------------------------
// K0b: fwd[n][d] = sum_w word[n][w] * W2[d][w]; emits
//   wpack[n][d] = { 2*log2(e)*fwd, -2*v[d] }
// k2a computes logit' = sum_d wy / (1 + 2^(F*wx)) = ref logit - sum(v)
// (s-uniform constant, cancels in softmax over s). Runs after k0_v.
// ---------------------------------------------------------------------------
__global__ __launch_bounds__(256) void k0_fwd(const float* __restrict__ word,
                                              const float* __restrict__ W2,
                                              const float* __restrict__ v,
                                              float2* __restrict__ wpack) {
    __shared__ __align__(16) float lword[NW];
    int n = blockIdx.x;
    int d = blockIdx.y * 256 + threadIdx.x;
    for (int i = threadIdx.x; i < NW; i += 256) lword[i] = word[(size_t)n * NW + i];
    __syncthreads();
    const float4* wr = (const float4*)(W2 + (size_t)d * NW);
    const float4* l4 = (const float4*)lword;
    float acc = 0.f;
    #pragma unroll 5
    for (int i = 0; i < NW / 4; ++i) {
        float4 a = wr[i], b = l4[i];
        acc += a.x * b.x + a.y * b.y + a.z * b.z + a.w * b.w;
    }
    float2 o;
    o.x = 2.8853900817779268f * acc;   // 2*log2(e) * fwd[n][d]
    o.y = -2.f * v[d];
    wpack[(size_t)n * ND + d] = o;
}

// ---------------------------------------------------------------------------
// Cast W1 [1024][2048] fp32 -> bf16, same layout.
// ---------------------------------------------------------------------------
__global__ __launch_bounds__(256) void kcast_w1(const float* __restrict__ W1,
                                                __bf16* __restrict__ O) {
    size_t i = ((size_t)blockIdx.x * 256 + threadIdx.x) * 4;
    float4 f = *(const float4*)(W1 + i);
    v4bf o;
    o[0] = (__bf16)f.x; o[1] = (__bf16)f.y; o[2] = (__bf16)f.z; o[3] = (__bf16)f.w;
    *(v4bf*)(O + i) = o;
}

// ---------------------------------------------------------------------------
// kcast_x: ONE pass over X [b][c][s] fp32 producing
//   Xt  [b][s][c]  bf16 (transposed, for k1 A/B staging)
//   Xhi/Xlo [b][c][224] bf16 split (for k3), zero s-pad
// grid (32 c-tiles, 4 s-tiles, 8 b), block 256. LDS-tiled 64x64.
// ---------------------------------------------------------------------------
__global__ __launch_bounds__(256) void kcast_x(const float* __restrict__ X,
                                               __bf16* __restrict__ Xt,
                                               __bf16* __restrict__ Xhi,
                                               __bf16* __restrict__ Xlo) {
    __shared__ float tile[64][65];   // [c][s], +1 pad
    const int b  = blockIdx.z;
    const int c0 = blockIdx.x * 64;
    const int s0 = blockIdx.y * 64;
    const int t  = threadIdx.x;
    const float* Xb = X + (size_t)b * NC * SB;
    {   // read: coalesced over s
        int ss = t & 63, cbase = t >> 6;
        #pragma unroll
        for (int r = 0; r < 16; ++r) {
            int cc = cbase + 4 * r;
            float val = (s0 + ss < SB) ? Xb[(size_t)(c0 + cc) * SB + s0 + ss] : 0.f;
            tile[cc][ss] = val;
        }
    }
    __syncthreads();
    {   // write 1: Xt transposed, coalesced over c
        int cc = t & 63, sbase = t >> 6;
        #pragma unroll
        for (int r = 0; r < 16; ++r) {
            int ss = sbase + 4 * r;
            if (s0 + ss < SB)
                Xt[((size_t)b * SB + s0 + ss) * NC + c0 + cc] = (__bf16)tile[cc][ss];
        }
    }
    {   // write 2: Xhi/Xlo direct orientation, coalesced over s; zero the pad
        int ss = t & 63, cbase = t >> 6;
        int sg = s0 + ss;
        #pragma unroll
        for (int r = 0; r < 16; ++r) {
            int cc = cbase + 4 * r;
            if (sg < SP) {
                float val = (sg < SB) ? tile[cc][ss] : 0.f;
                __bf16 h = (__bf16)val;
                __bf16 l = (__bf16)(val - (float)h);
                size_t base = ((size_t)b * NC + c0 + cc) * SP + sg;
                Xhi[base] = h;
                Xlo[base] = l;
            }
        }
    }
}

// ---------------------------------------------------------------------------
// K1 (MFMA): F[b][d][s] = sum_c W1[d][c] * X[b][c][s], bf16 inputs, fp32 out.
// Block tile 64d x 64s, 4 waves each own a 32x32 quadrant (2x2 16x16 frags).
// K-step 32. grid (16 d-tiles, 4 s-tiles, 8 b), block 256.
// EXACT R3/R6/R7-proven version (the BK=64+prefetch variant is banned: it was
// the isolated cause of the R4/R5 post-timing divergence).
// ---------------------------------------------------------------------------
#define PITCH 40
__global__ __launch_bounds__(256) void k1_mfma(const __bf16* __restrict__ Xt,
                                               const __bf16* __restrict__ W1b,
                                               float* __restrict__ F) {
    __shared__ __align__(16) __bf16 lA[64 * PITCH];
    __shared__ __align__(16) __bf16 lB[64 * PITCH];
    const int t    = threadIdx.x;
    const int d0   = blockIdx.x * 64;
    const int s0   = blockIdx.y * 64;
    const int b    = blockIdx.z;
    const int lane = t & 63;
    const int wave = t >> 6;
    const int doff = (wave & 1) * 32;
    const int soff = (wave >> 1) * 32;
    const int quad = lane >> 4;
    const int l16  = lane & 15;

    f32x4 acc[2][2] = {};

    const int rr = t >> 2;
    const int cc = (t & 3) * 8;
    const bool sv = (s0 + rr) < SB;
    const __bf16* Ag = W1b + (size_t)(d0 + rr) * NC + cc;
    const __bf16* Bg = Xt + ((size_t)b * SB + (sv ? (s0 + rr) : 0)) * NC + cc;
    __bf16* lAw = lA + rr * PITCH + cc;
    __bf16* lBw = lB + rr * PITCH + cc;

    const __bf16* rA0 = lA + (doff + l16) * PITCH + quad * 8;
    const __bf16* rA1 = rA0 + 16 * PITCH;
    const __bf16* rB0 = lB + (soff + l16) * PITCH + quad * 8;
    const __bf16* rB1 = rB0 + 16 * PITCH;

    for (int k0 = 0; k0 < NC; k0 += 32) {
        uint4 a = *(const uint4*)(Ag + k0);
        uint4 bv = sv ? *(const uint4*)(Bg + k0) : make_uint4(0u, 0u, 0u, 0u);
        __syncthreads();
        *(uint4*)lAw = a;
        *(uint4*)lBw = bv;
        __syncthreads();
        v8bf a0 = *(const v8bf*)rA0;
        v8bf a1 = *(const v8bf*)rA1;
        v8bf b0 = *(const v8bf*)rB0;
        v8bf b1 = *(const v8bf*)rB1;
        acc[0][0] = __builtin_amdgcn_mfma_f32_16x16x32_bf16(a0, b0, acc[0][0], 0, 0, 0);
        acc[0][1] = __builtin_amdgcn_mfma_f32_16x16x32_bf16(a0, b1, acc[0][1], 0, 0, 0);
        acc[1][0] = __builtin_amdgcn_mfma_f32_16x16x32_bf16(a1, b0, acc[1][0], 0, 0, 0);
        acc[1][1] = __builtin_amdgcn_mfma_f32_16x16x32_bf16(a1, b1, acc[1][1], 0, 0, 0);
    }
    float* Fb = F + (size_t)b * ND * SB;
    #pragma unroll
    for (int i = 0; i < 2; ++i) {
        #pragma unroll
        for (int j = 0; j < 2; ++j) {
            int s = s0 + soff + j * 16 + l16;
            if (s < SB) {
                #pragma unroll
                for (int r = 0; r < 4; ++r) {
                    int d = d0 + doff + i * 16 + quad * 4 + r;
                    Fb[(size_t)d * SB + s] = acc[i][j][r];
                }
            }
        }
    }
}

// ---------------------------------------------------------------------------
// K2a v2: partial logits, flattened (b,s) for lane packing + d-pair ILP.
// part[ch][b][n][s] = sum_{d in chunk} wy/(1 + 2^(F*wx))
// grid (80 n, 7 bs-tiles, 4 ch), block 256: idx = by*256+t over 1568 (b,s).
// ch is block-uniform -> wpack pairs via wave-uniform s_load_dwordx4.
// ---------------------------------------------------------------------------
__global__ __launch_bounds__(256) void k2a(const float* __restrict__ F,
                                           const float2* __restrict__ wpack,
                                           float* __restrict__ part) {
    const int n   = blockIdx.x;
    const int ch  = blockIdx.z;
    const int idx = blockIdx.y * 256 + threadIdx.x;   // (b,s) flat, valid <1568
    const bool valid = idx < (NB * SB);
    const int iv = valid ? idx : 0;
    const int b  = iv / SB;          // magic-mul div by 196
    const int s  = iv - b * SB;
    const float*  Fp  = F + ((size_t)b * ND + ch * DCH) * SB + s;
    const float4* wp4 = (const float4*)(wpack + (size_t)n * ND + ch * DCH);
    float acc = 0.f;
    #pragma unroll 4
    for (int d2 = 0; d2 < DCH / 2; ++d2) {
        float4 w = wp4[d2];                            // {wx0,wy0,wx1,wy1} s_load
        float x0 = Fp[(size_t)(2 * d2)     * SB] * w.x;
        float x1 = Fp[(size_t)(2 * d2 + 1) * SB] * w.z;
        float e0 = __builtin_amdgcn_exp2f(x0);         // 2 independent chains
        float e1 = __builtin_amdgcn_exp2f(x1);
        float r0 = __builtin_amdgcn_rcpf(1.f + e0);
        float r1 = __builtin_amdgcn_rcpf(1.f + e1);
        acc = fmaf(w.y, r0, acc);
        acc = fmaf(w.w, r1, acc);
    }
    if (valid)
        part[(((size_t)ch * NB + b) * NN + n) * 256 + s] = acc;
}

// ---------------------------------------------------------------------------
// K2b: sum 4 chunks, softmax over s, write split bf16 coef (SP-padded).
// grid (80 n, 8 b), block 256. part slots s in [196,256) are never written
// (finite poison); they only reach acc for t>=SB, which is masked below.
// ---------------------------------------------------------------------------
__global__ __launch_bounds__(256) void k2b(const float* __restrict__ part,
                                           __bf16* __restrict__ coefh,
                                           __bf16* __restrict__ coefl) {
    __shared__ float red[256];
    const int n = blockIdx.x;
    const int b = blockIdx.y;
    const int t = threadIdx.x;
    float acc = 0.f;
    #pragma unroll
    for (int ch = 0; ch < CH; ++ch)
        acc += part[(((size_t)ch * NB + b) * NN + n) * 256 + t];

    red[t] = (t < SB) ? acc : -1e30f;
    __syncthreads();
    #pragma unroll
    for (int off = 128; off > 0; off >>= 1) {
        if (t < off) red[t] = fmaxf(red[t], red[t + off]);
        __syncthreads();
    }
    float m = red[0];
    __syncthreads();
    float p = (t < SB) ? __expf(acc - m) : 0.f;
    red[t] = p;
    __syncthreads();
    #pragma unroll
    for (int off = 128; off > 0; off >>= 1) {
        if (t < off) red[t] += red[t + off];
        __syncthreads();
    }
    float inv = 1.f / red[0];
    if (t < SP) {
        float val = (t < SB) ? p * inv : 0.f;
        __bf16 h = (__bf16)val;
        __bf16 l = (__bf16)(val - (float)h);
        size_t base = ((size_t)b * NN + n) * SP + t;
        coefh[base] = h;
        coefl[base] = l;
    }
}

// ---------------------------------------------------------------------------
// K3 (MFMA, split precision): out[b][n][c] = sum_s coef[b][n][s] * X[b][c][s]
// out ~= Ah*Bh + Al*Bh + Ah*Bl. grid (32 c-tiles, 8 b), block 256.
// ---------------------------------------------------------------------------
__global__ __launch_bounds__(256) void k3_mfma(const __bf16* __restrict__ Xhi,
                                               const __bf16* __restrict__ Xlo,
                                               const __bf16* __restrict__ coefh,
                                               const __bf16* __restrict__ coefl,
                                               float* __restrict__ out) {
    const int t     = threadIdx.x;
    const int wave  = t >> 6;
    const int lane  = t & 63;
    const int quad  = lane >> 4;
    const int l16   = lane & 15;
    const int b     = blockIdx.y;
    const int cbase = blockIdx.x * 64 + wave * 16;

    const __bf16* Bh = Xhi + ((size_t)b * NC + cbase + l16) * SP + quad * 8;
    const __bf16* Bl = Xlo + ((size_t)b * NC + cbase + l16) * SP + quad * 8;
    const __bf16* Ah = coefh + ((size_t)b * NN + l16) * SP + quad * 8;
    const __bf16* Al = coefl + ((size_t)b * NN + l16) * SP + quad * 8;

    f32x4 acc[5] = {};

    #pragma unroll
    for (int k0 = 0; k0 < SP; k0 += 32) {
        v8bf bh = *(const v8bf*)(Bh + k0);
        v8bf bl = *(const v8bf*)(Bl + k0);
        #pragma unroll
        for (int mt = 0; mt < 5; ++mt) {
            v8bf ah = *(const v8bf*)(Ah + (size_t)mt * 16 * SP + k0);
            v8bf al = *(const v8bf*)(Al + (size_t)mt * 16 * SP + k0);
            acc[mt] = __builtin_amdgcn_mfma_f32_16x16x32_bf16(ah, bh, acc[mt], 0, 0, 0);
            acc[mt] = __builtin_amdgcn_mfma_f32_16x16x32_bf16(al, bh, acc[mt], 0, 0, 0);
            acc[mt] = __builtin_amdgcn_mfma_f32_16x16x32_bf16(ah, bl, acc[mt], 0, 0, 0);
        }
    }
    #pragma unroll
    for (int mt = 0; mt < 5; ++mt) {
        #pragma unroll
        for (int r = 0; r < 4; ++r) {
            int n = mt * 16 + quad * 4 + r;
            out[((size_t)b * NN + n) * NC + cbase + l16] = acc[mt][r];
        }
    }
}

// ---------------------------------------------------------------------------
// Workspace layout — NO aliasing (ws_size ~256 MB per fillBufferAligned
// counter; peak use ~35.4 MB):
//   v(4K) | wpack(640K) | part(2.62M) | coefh(280K) | coefl(280K) |
//   W1b(4M) | Xt(6.42M) | F(6.42M) | Xhi(7.34M) | Xlo(7.34M)
// ---------------------------------------------------------------------------
extern "C" void kernel_launch(void* const* d_in, const int* in_sizes, int n_in,
                              void* d_out, int out_size, void* d_ws, size_t ws_size,
                              hipStream_t stream) {
    const float* X    = (const float*)d_in[0];  // [8][2048][196]
    const float* word = (const float*)d_in[1];  // [80][300]
    const float* W1   = (const float*)d_in[2];  // [1024][2048]
    const float* W2   = (const float*)d_in[3];  // [1024][300]
    const float* W3   = (const float*)d_in[4];  // [1024][1024]
    // d_in[5] = b3, d_in[7] = ba: cancel in softmax (uniform over s) -> unused
    const float* Wa   = (const float*)d_in[6];  // [1][1024]
    float* out = (float*)d_out;

    char* ws = (char*)d_ws;
    float*  v     = (float*)ws;                             // 1024 f
    float2* wpack = (float2*)(v + ND);                      // 80*1024 float2
    float*  part  = (float*)(wpack + (size_t)NN * ND);      // 4*8*80*256 f
    __bf16* coefh = (__bf16*)(part + (size_t)CH * NB * NN * 256);
    __bf16* coefl = coefh + (size_t)NB * NN * SP;
    __bf16* W1b   = coefl + (size_t)NB * NN * SP;           // 4.00 MB
    __bf16* Xt    = W1b + (size_t)ND * NC;                  // 6.42 MB
    float*  F     = (float*)(Xt + (size_t)NB * SB * NC);    // 6.42 MB
    __bf16* Xhi   = (__bf16*)(F + (size_t)NB * ND * SB);    // 7.34 MB
    __bf16* Xlo   = Xhi + (size_t)NB * NC * SP;             // 7.34 MB

    hipMemsetAsync(v, 0, ND * sizeof(float), stream);
    k0_v    <<<dim3(4, 16),                 256, 0, stream>>>(W3, Wa, v);
    k0_fwd  <<<dim3(NN, 4),                 256, 0, stream>>>(word, W2, v, wpack);
    kcast_w1<<<dim3((ND * NC) / (256 * 4)), 256, 0, stream>>>(W1, W1b);
    kcast_x <<<dim3(32, 4, NB),             256, 0, stream>>>(X, Xt, Xhi, Xlo);
    k1_mfma <<<dim3(16, 4, NB),             256, 0, stream>>>(Xt, W1b, F);
    k2a     <<<dim3(NN, 7, CH),             256, 0, stream>>>(F, wpack, part);
    k2b     <<<dim3(NN, NB),                256, 0, stream>>>(part, coefh, coefl);
    k3_mfma <<<dim3(NC / 64, NB),           256, 0, stream>>>(Xhi, Xlo, coefh, coefl, out);
}

// Round 9
// 188.015 us; speedup vs baseline: 3.2279x; 1.0240x over previous
//
#include <hip/hip_runtime.h>
#include <math.h>

// Problem constants (match reference setup_inputs)
#define SB 196   // spatial s = h*w = 14*14
#define SP 224   // s padded to 7*32 for MFMA K-steps
#define NB 8     // batch
#define NC 2048  // channels
#define ND 1024  // INTER_DIM
#define NN 80    // NUM_CLASSES
#define NW 300   // WORD_DIM
#define CH 8     // d-chunks in k2a
#define DCH (ND / CH)

typedef __bf16 v8bf __attribute__((ext_vector_type(8)));
typedef __bf16 v4bf __attribute__((ext_vector_type(4)));
typedef __bf16 v2bf __attribute__((ext_vector_type(2)));
typedef float  f32x4 __attribute__((ext_vector_type(4)));

// ---------------------------------------------------------------------------
// K0a: v[d] = sum_e Wa[e] * W3[e][d]   (Wa @ W3), accumulated via atomics.
// ---------------------------------------------------------------------------
__global__ __launch_bounds__(256) void k0_v(const float* __restrict__ W3,
                                            const float* __restrict__ Wa,
                                            float* __restrict__ v) {
    int d  = blockIdx.x * 256 + threadIdx.x;
    int e0 = blockIdx.y * 64;
    float p = 0.f;
    #pragma unroll 8
    for (int e = e0; e < e0 + 64; ++e) {
        p += Wa[e] * W3[(size_t)e * ND + d];   // coalesced over d
    }
    atomicAdd(&v[d], p);
}

// ---------------------------------------------------------------------------
// K0b: fwd[n][d] = sum_w word[n][w] * W2[d][w]; emits
//   wpack[n][d] = { 2*log2(e)*fwd, -2*v[d] }
// k2a computes logit' = sum_d wy / (1 + 2^(F*wx)) = ref logit - sum(v)
// (s-uniform constant, cancels in softmax over s). Runs after k0_v.
// ---------------------------------------------------------------------------
__global__ __launch_bounds__(256) void k0_fwd(const float* __restrict__ word,
                                              const float* __restrict__ W2,
                                              const float* __restrict__ v,
                                              float2* __restrict__ wpack) {
    __shared__ __align__(16) float lword[NW];
    int n = blockIdx.x;
    int d = blockIdx.y * 256 + threadIdx.x;
    for (int i = threadIdx.x; i < NW; i += 256) lword[i] = word[(size_t)n * NW + i];
    __syncthreads();
    const float4* wr = (const float4*)(W2 + (size_t)d * NW);
    const float4* l4 = (const float4*)lword;
    float acc = 0.f;
    #pragma unroll 5
    for (int i = 0; i < NW / 4; ++i) {
        float4 a = wr[i], b = l4[i];
        acc += a.x * b.x + a.y * b.y + a.z * b.z + a.w * b.w;
    }
    float2 o;
    o.x = 2.8853900817779268f * acc;   // 2*log2(e) * fwd[n][d]
    o.y = -2.f * v[d];
    wpack[(size_t)n * ND + d] = o;
}

// ---------------------------------------------------------------------------
// kcast_x: ONE pass over X [b][c][s] fp32 producing
//   Xt  [b][s][c]  bf16 (transposed, for k1 A/B staging)
//   Xhi/Xlo [b][c][224] bf16 split (for k3), zero s-pad
// grid (32 c-tiles, 4 s-tiles, 9): z<8 = batch slice; z==8 = W1 fp32->bf16
// cast slice (fused former kcast_w1 to save one dispatch).
// ---------------------------------------------------------------------------
__global__ __launch_bounds__(256) void kcast_x(const float* __restrict__ X,
                                               const float* __restrict__ W1,
                                               __bf16* __restrict__ Xt,
                                               __bf16* __restrict__ Xhi,
                                               __bf16* __restrict__ Xlo,
                                               __bf16* __restrict__ W1b) {
    const int t = threadIdx.x;
    if (blockIdx.z == 8) {
        // W1 cast: 128 blocks x 256 threads x 16 float4 = 2M elems
        unsigned int slice_tid = (blockIdx.x * 4 + blockIdx.y) * 256 + t;
        #pragma unroll 4
        for (int r = 0; r < 16; ++r) {
            size_t i = ((size_t)slice_tid + (size_t)r * 32768) * 4;
            float4 f = *(const float4*)(W1 + i);
            v4bf o;
            o[0] = (__bf16)f.x; o[1] = (__bf16)f.y;
            o[2] = (__bf16)f.z; o[3] = (__bf16)f.w;
            *(v4bf*)(W1b + i) = o;
        }
        return;
    }
    __shared__ float tile[64][65];   // [c][s], +1 pad
    const int b  = blockIdx.z;
    const int c0 = blockIdx.x * 64;
    const int s0 = blockIdx.y * 64;
    const float* Xb = X + (size_t)b * NC * SB;
    {   // read: coalesced over s
        int ss = t & 63, cbase = t >> 6;
        #pragma unroll
        for (int r = 0; r < 16; ++r) {
            int cc = cbase + 4 * r;
            float val = (s0 + ss < SB) ? Xb[(size_t)(c0 + cc) * SB + s0 + ss] : 0.f;
            tile[cc][ss] = val;
        }
    }
    __syncthreads();
    {   // write 1: Xt transposed, coalesced over c
        int cc = t & 63, sbase = t >> 6;
        #pragma unroll
        for (int r = 0; r < 16; ++r) {
            int ss = sbase + 4 * r;
            if (s0 + ss < SB)
                Xt[((size_t)b * SB + s0 + ss) * NC + c0 + cc] = (__bf16)tile[cc][ss];
        }
    }
    {   // write 2: Xhi/Xlo direct orientation, coalesced over s; zero the pad
        int ss = t & 63, cbase = t >> 6;
        int sg = s0 + ss;
        #pragma unroll
        for (int r = 0; r < 16; ++r) {
            int cc = cbase + 4 * r;
            if (sg < SP) {
                float val = (sg < SB) ? tile[cc][ss] : 0.f;
                __bf16 h = (__bf16)val;
                __bf16 l = (__bf16)(val - (float)h);
                size_t base = ((size_t)b * NC + c0 + cc) * SP + sg;
                Xhi[base] = h;
                Xlo[base] = l;
            }
        }
    }
}

// ---------------------------------------------------------------------------
// K1 (MFMA): F[b][d][s] = sum_c W1[d][c] * X[b][c][s], bf16 inputs, fp32 out.
// Block tile 64d x 64s, 4 waves each own a 32x32 quadrant (2x2 16x16 frags).
// K-step 32. grid (16 d-tiles, 4 s-tiles, 8 b), block 256.
// EXACT R3/R6/R7/R8-proven version (BK=64+prefetch variant stays banned).
// ---------------------------------------------------------------------------
#define PITCH 40
__global__ __launch_bounds__(256) void k1_mfma(const __bf16* __restrict__ Xt,
                                               const __bf16* __restrict__ W1b,
                                               float* __restrict__ F) {
    __shared__ __align__(16) __bf16 lA[64 * PITCH];
    __shared__ __align__(16) __bf16 lB[64 * PITCH];
    const int t    = threadIdx.x;
    const int d0   = blockIdx.x * 64;
    const int s0   = blockIdx.y * 64;
    const int b    = blockIdx.z;
    const int lane = t & 63;
    const int wave = t >> 6;
    const int doff = (wave & 1) * 32;
    const int soff = (wave >> 1) * 32;
    const int quad = lane >> 4;
    const int l16  = lane & 15;

    f32x4 acc[2][2] = {};

    const int rr = t >> 2;
    const int cc = (t & 3) * 8;
    const bool sv = (s0 + rr) < SB;
    const __bf16* Ag = W1b + (size_t)(d0 + rr) * NC + cc;
    const __bf16* Bg = Xt + ((size_t)b * SB + (sv ? (s0 + rr) : 0)) * NC + cc;
    __bf16* lAw = lA + rr * PITCH + cc;
    __bf16* lBw = lB + rr * PITCH + cc;

    const __bf16* rA0 = lA + (doff + l16) * PITCH + quad * 8;
    const __bf16* rA1 = rA0 + 16 * PITCH;
    const __bf16* rB0 = lB + (soff + l16) * PITCH + quad * 8;
    const __bf16* rB1 = rB0 + 16 * PITCH;

    for (int k0 = 0; k0 < NC; k0 += 32) {
        uint4 a = *(const uint4*)(Ag + k0);
        uint4 bv = sv ? *(const uint4*)(Bg + k0) : make_uint4(0u, 0u, 0u, 0u);
        __syncthreads();
        *(uint4*)lAw = a;
        *(uint4*)lBw = bv;
        __syncthreads();
        v8bf a0 = *(const v8bf*)rA0;
        v8bf a1 = *(const v8bf*)rA1;
        v8bf b0 = *(const v8bf*)rB0;
        v8bf b1 = *(const v8bf*)rB1;
        acc[0][0] = __builtin_amdgcn_mfma_f32_16x16x32_bf16(a0, b0, acc[0][0], 0, 0, 0);
        acc[0][1] = __builtin_amdgcn_mfma_f32_16x16x32_bf16(a0, b1, acc[0][1], 0, 0, 0);
        acc[1][0] = __builtin_amdgcn_mfma_f32_16x16x32_bf16(a1, b0, acc[1][0], 0, 0, 0);
        acc[1][1] = __builtin_amdgcn_mfma_f32_16x16x32_bf16(a1, b1, acc[1][1], 0, 0, 0);
    }
    float* Fb = F + (size_t)b * ND * SB;
    #pragma unroll
    for (int i = 0; i < 2; ++i) {
        #pragma unroll
        for (int j = 0; j < 2; ++j) {
            int s = s0 + soff + j * 16 + l16;
            if (s < SB) {
                #pragma unroll
                for (int r = 0; r < 4; ++r) {
                    int d = d0 + doff + i * 16 + quad * 4 + r;
                    Fb[(size_t)d * SB + s] = acc[i][j][r];
                }
            }
        }
    }
}

// ---------------------------------------------------------------------------
// K2a v3: partial logits with 4-way n-tiling (each F element reused for 4 n).
// part[ch][b][n][s] = sum_{d in chunk} wy/(1 + 2^(F*wx))
// grid (20 n-groups, 7 bs-tiles, 8 ch), block 256: idx = by*256+t over (b,s).
// Per d-pair iter: 2 F loads amortized over 4 n -> 8 independent tanh chains
// (16 trans + 24 VALU per 2 loads). wpack via wave-uniform s_load_dwordx4.
// ---------------------------------------------------------------------------
__global__ __launch_bounds__(256) void k2a(const float* __restrict__ F,
                                           const float2* __restrict__ wpack,
                                           float* __restrict__ part) {
    const int n0  = blockIdx.x * 4;
    const int ch  = blockIdx.z;
    const int idx = blockIdx.y * 256 + threadIdx.x;   // (b,s) flat, valid <1568
    const bool valid = idx < (NB * SB);
    const int iv = valid ? idx : 0;
    const int b  = iv / SB;          // magic-mul div by 196
    const int s  = iv - b * SB;
    const float*  Fp  = F + ((size_t)b * ND + ch * DCH) * SB + s;
    const float4* wp0 = (const float4*)(wpack + (size_t)(n0 + 0) * ND + ch * DCH);
    const float4* wp1 = (const float4*)(wpack + (size_t)(n0 + 1) * ND + ch * DCH);
    const float4* wp2 = (const float4*)(wpack + (size_t)(n0 + 2) * ND + ch * DCH);
    const float4* wp3 = (const float4*)(wpack + (size_t)(n0 + 3) * ND + ch * DCH);
    float a0 = 0.f, a1 = 0.f, a2 = 0.f, a3 = 0.f;
    #pragma unroll 4
    for (int d2 = 0; d2 < DCH / 2; ++d2) {
        float f0 = Fp[(size_t)(2 * d2)     * SB];
        float f1 = Fp[(size_t)(2 * d2 + 1) * SB];
        float4 w0 = wp0[d2];   // {wx0, wy0, wx1, wy1} wave-uniform s_load
        float4 w1 = wp1[d2];
        float4 w2 = wp2[d2];
        float4 w3 = wp3[d2];
        float e00 = __builtin_amdgcn_exp2f(f0 * w0.x);
        float e01 = __builtin_amdgcn_exp2f(f1 * w0.z);
        float e10 = __builtin_amdgcn_exp2f(f0 * w1.x);
        float e11 = __builtin_amdgcn_exp2f(f1 * w1.z);
        float e20 = __builtin_amdgcn_exp2f(f0 * w2.x);
        float e21 = __builtin_amdgcn_exp2f(f1 * w2.z);
        float e30 = __builtin_amdgcn_exp2f(f0 * w3.x);
        float e31 = __builtin_amdgcn_exp2f(f1 * w3.z);
        a0 = fmaf(w0.y, __builtin_amdgcn_rcpf(1.f + e00), a0);
        a0 = fmaf(w0.w, __builtin_amdgcn_rcpf(1.f + e01), a0);
        a1 = fmaf(w1.y, __builtin_amdgcn_rcpf(1.f + e10), a1);
        a1 = fmaf(w1.w, __builtin_amdgcn_rcpf(1.f + e11), a1);
        a2 = fmaf(w2.y, __builtin_amdgcn_rcpf(1.f + e20), a2);
        a2 = fmaf(w2.w, __builtin_amdgcn_rcpf(1.f + e21), a2);
        a3 = fmaf(w3.y, __builtin_amdgcn_rcpf(1.f + e30), a3);
        a3 = fmaf(w3.w, __builtin_amdgcn_rcpf(1.f + e31), a3);
    }
    if (valid) {
        size_t base = ((size_t)ch * NB + b) * NN;
        part[(base + n0 + 0) * 256 + s] = a0;
        part[(base + n0 + 1) * 256 + s] = a1;
        part[(base + n0 + 2) * 256 + s] = a2;
        part[(base + n0 + 3) * 256 + s] = a3;
    }
}

// ---------------------------------------------------------------------------
// K2b: sum 8 chunks, softmax over s, write split bf16 coef (SP-padded).
// grid (80 n, 8 b), block 256. part slots s in [196,256) are never written
// (finite poison); they only reach acc for t>=SB, which is masked below.
// ---------------------------------------------------------------------------
__global__ __launch_bounds__(256) void k2b(const float* __restrict__ part,
                                           __bf16* __restrict__ coefh,
                                           __bf16* __restrict__ coefl) {
    __shared__ float red[256];
    const int n = blockIdx.x;
    const int b = blockIdx.y;
    const int t = threadIdx.x;
    float acc = 0.f;
    #pragma unroll
    for (int ch = 0; ch < CH; ++ch)
        acc += part[(((size_t)ch * NB + b) * NN + n) * 256 + t];

    red[t] = (t < SB) ? acc : -1e30f;
    __syncthreads();
    #pragma unroll
    for (int off = 128; off > 0; off >>= 1) {
        if (t < off) red[t] = fmaxf(red[t], red[t + off]);
        __syncthreads();
    }
    float m = red[0];
    __syncthreads();
    float p = (t < SB) ? __expf(acc - m) : 0.f;
    red[t] = p;
    __syncthreads();
    #pragma unroll
    for (int off = 128; off > 0; off >>= 1) {
        if (t < off) red[t] += red[t + off];
        __syncthreads();
    }
    float inv = 1.f / red[0];
    if (t < SP) {
        float val = (t < SB) ? p * inv : 0.f;
        __bf16 h = (__bf16)val;
        __bf16 l = (__bf16)(val - (float)h);
        size_t base = ((size_t)b * NN + n) * SP + t;
        coefh[base] = h;
        coefl[base] = l;
    }
}

// ---------------------------------------------------------------------------
// K3 (MFMA, split precision): out[b][n][c] = sum_s coef[b][n][s] * X[b][c][s]
// out ~= Ah*Bh + Al*Bh + Ah*Bl. grid (32 c-tiles, 8 b), block 256.
// ---------------------------------------------------------------------------
__global__ __launch_bounds__(256) void k3_mfma(const __bf16* __restrict__ Xhi,
                                               const __bf16* __restrict__ Xlo,
                                               const __bf16* __restrict__ coefh,
                                               const __bf16* __restrict__ coefl,
                                               float* __restrict__ out) {
    const int t     = threadIdx.x;
    const int wave  = t >> 6;
    const int lane  = t & 63;
    const int quad  = lane >> 4;
    const int l16   = lane & 15;
    const int b     = blockIdx.y;
    const int cbase = blockIdx.x * 64 + wave * 16;

    const __bf16* Bh = Xhi + ((size_t)b * NC + cbase + l16) * SP + quad * 8;
    const __bf16* Bl = Xlo + ((size_t)b * NC + cbase + l16) * SP + quad * 8;
    const __bf16* Ah = coefh + ((size_t)b * NN + l16) * SP + quad * 8;
    const __bf16* Al = coefl + ((size_t)b * NN + l16) * SP + quad * 8;

    f32x4 acc[5] = {};

    #pragma unroll
    for (int k0 = 0; k0 < SP; k0 += 32) {
        v8bf bh = *(const v8bf*)(Bh + k0);
        v8bf bl = *(const v8bf*)(Bl + k0);
        #pragma unroll
        for (int mt = 0; mt < 5; ++mt) {
            v8bf ah = *(const v8bf*)(Ah + (size_t)mt * 16 * SP + k0);
            v8bf al = *(const v8bf*)(Al + (size_t)mt * 16 * SP + k0);
            acc[mt] = __builtin_amdgcn_mfma_f32_16x16x32_bf16(ah, bh, acc[mt], 0, 0, 0);
            acc[mt] = __builtin_amdgcn_mfma_f32_16x16x32_bf16(al, bh, acc[mt], 0, 0, 0);
            acc[mt] = __builtin_amdgcn_mfma_f32_16x16x32_bf16(ah, bl, acc[mt], 0, 0, 0);
        }
    }
    #pragma unroll
    for (int mt = 0; mt < 5; ++mt) {
        #pragma unroll
        for (int r = 0; r < 4; ++r) {
            int n = mt * 16 + quad * 4 + r;
            out[((size_t)b * NN + n) * NC + cbase + l16] = acc[mt][r];
        }
    }
}

// ---------------------------------------------------------------------------
// Workspace layout — NO aliasing (ws ~256 MB; peak use ~38 MB):
//   v(4K) | wpack(640K) | part(5.24M) | coefh(280K) | coefl(280K) |
//   W1b(4M) | Xt(6.42M) | F(6.42M) | Xhi(7.34M) | Xlo(7.34M)
// ---------------------------------------------------------------------------
extern "C" void kernel_launch(void* const* d_in, const int* in_sizes, int n_in,
                              void* d_out, int out_size, void* d_ws, size_t ws_size,
                              hipStream_t stream) {
    const float* X    = (const float*)d_in[0];  // [8][2048][196]
    const float* word = (const float*)d_in[1];  // [80][300]
    const float* W1   = (const float*)d_in[2];  // [1024][2048]
    const float* W2   = (const float*)d_in[3];  // [1024][300]
    const float* W3   = (const float*)d_in[4];  // [1024][1024]
    // d_in[5] = b3, d_in[7] = ba: cancel in softmax (uniform over s) -> unused
    const float* Wa   = (const float*)d_in[6];  // [1][1024]
    float* out = (float*)d_out;

    char* ws = (char*)d_ws;
    float*  v     = (float*)ws;                             // 1024 f
    float2* wpack = (float2*)(v + ND);                      // 80*1024 float2
    float*  part  = (float*)(wpack + (size_t)NN * ND);      // 8*8*80*256 f
    __bf16* coefh = (__bf16*)(part + (size_t)CH * NB * NN * 256);
    __bf16* coefl = coefh + (size_t)NB * NN * SP;
    __bf16* W1b   = coefl + (size_t)NB * NN * SP;           // 4.00 MB
    __bf16* Xt    = W1b + (size_t)ND * NC;                  // 6.42 MB
    float*  F     = (float*)(Xt + (size_t)NB * SB * NC);    // 6.42 MB
    __bf16* Xhi   = (__bf16*)(F + (size_t)NB * ND * SB);    // 7.34 MB
    __bf16* Xlo   = Xhi + (size_t)NB * NC * SP;             // 7.34 MB

    hipMemsetAsync(v, 0, ND * sizeof(float), stream);
    k0_v   <<<dim3(4, 16),       256, 0, stream>>>(W3, Wa, v);
    k0_fwd <<<dim3(NN, 4),       256, 0, stream>>>(word, W2, v, wpack);
    kcast_x<<<dim3(32, 4, 9),    256, 0, stream>>>(X, W1, Xt, Xhi, Xlo, W1b);
    k1_mfma<<<dim3(16, 4, NB),   256, 0, stream>>>(Xt, W1b, F);
    k2a    <<<dim3(NN / 4, 7, CH), 256, 0, stream>>>(F, wpack, part);
    k2b    <<<dim3(NN, NB),      256, 0, stream>>>(part, coefh, coefl);
    k3_mfma<<<dim3(NC / 64, NB), 256, 0, stream>>>(Xhi, Xlo, coefh, coefl, out);
}